// Round 1
// baseline (680.141 us; speedup 1.0000x reference)
//
#include <hip/hip_runtime.h>

// ---------------------------------------------------------------------------
// DecoderBlock: B=2, T=2048, C=768, H=12, d=64
// Pipeline (all bf16 MFMA with fp32 accum; residual stream kept in fp32):
//   qkv = x@Wqkv+b -> attn(causal) -> proj+b+res(x) -> LN1 -> x1
//   cq = x1@Wq+b ; ck,cv = enc@Wk/Wv+b -> attn(non-causal) -> o+b+res(x1) -> LN2 -> x2
//   h = relu(x2@Wfc+b) ; fc2(h)+b+res(x2) -> LN3 -> out (fp32)
// ---------------------------------------------------------------------------

#define C_EMBD 768
#define NHEAD  12
#define HD     64
#define TB     2048
#define BB     2
#define MTOK   (BB*TB)   // 4096 tokens

typedef __bf16 bf16_8 __attribute__((ext_vector_type(8)));
typedef float  f32x4  __attribute__((ext_vector_type(4)));

__device__ __forceinline__ unsigned short f2bf(float f) {
    union { float f; unsigned u; } x; x.f = f;
    unsigned r = x.u + 0x7FFFu + ((x.u >> 16) & 1u);   // RNE
    return (unsigned short)(r >> 16);
}

// ---------------- fp32 -> bf16 convert (4 el/thread) ----------------
__global__ __launch_bounds__(256) void k_conv_bf16(const float* __restrict__ in,
                                                   unsigned short* __restrict__ out) {
    int i = blockIdx.x * 256 + threadIdx.x;
    float4 v = ((const float4*)in)[i];
    ushort4 o;
    o.x = f2bf(v.x); o.y = f2bf(v.y); o.z = f2bf(v.z); o.w = f2bf(v.w);
    ((ushort4*)out)[i] = o;
}

// ------------- W (KxN fp32) -> Wt (NxK bf16) transpose -------------
__global__ __launch_bounds__(256) void k_transpose_w(const float* __restrict__ W,
                                                     unsigned short* __restrict__ Wt,
                                                     int K, int N) {
    __shared__ float tile[32][33];
    int tx = threadIdx.x, ty = threadIdx.y;
    int n0 = blockIdx.x * 32, k0 = blockIdx.y * 32;
#pragma unroll
    for (int i = 0; i < 4; ++i)
        tile[ty + 8*i][tx] = W[(size_t)(k0 + ty + 8*i) * N + n0 + tx];
    __syncthreads();
#pragma unroll
    for (int i = 0; i < 4; ++i)
        Wt[(size_t)(n0 + ty + 8*i) * K + k0 + tx] = f2bf(tile[tx][ty + 8*i]);
}

// ---------------- GEMM: C[MxN] = A[MxK] @ Bt[NxK]^T + bias (+res)(+relu) ----
// 256 thr = 4 waves (2x2), 128x128 tile, BK=32, 16x16x32 bf16 MFMA.
template<bool OUT_BF16, bool ADD_RES, bool RELU>
__global__ __launch_bounds__(256) void k_gemm_bt(
        const unsigned short* __restrict__ A,
        const unsigned short* __restrict__ Bt,
        const float* __restrict__ bias,
        const float* __restrict__ res,
        void* __restrict__ Cout,
        int M, int N, int K) {
    __shared__ unsigned short As[128][40];   // +8 pad: 80B rows, 16B-aligned
    __shared__ unsigned short Bs[128][40];
    int tid  = threadIdx.x;
    int lane = tid & 63, wave = tid >> 6;
    int l16 = lane & 15, lg = lane >> 4;
    int wm = (wave >> 1) * 64, wn = (wave & 1) * 64;
    int bm = blockIdx.x * 128, bn = blockIdx.y * 128;

    f32x4 acc[4][4] = {};

    for (int k0 = 0; k0 < K; k0 += 32) {
        __syncthreads();
#pragma unroll
        for (int i = 0; i < 2; ++i) {
            int chunk = tid + i * 256;            // 512 chunks of 8 bf16
            int r = chunk >> 2, cc = (chunk & 3) * 8;
            *(int4*)(&As[r][cc]) = *(const int4*)(A  + (size_t)(bm + r) * K + k0 + cc);
            *(int4*)(&Bs[r][cc]) = *(const int4*)(Bt + (size_t)(bn + r) * K + k0 + cc);
        }
        __syncthreads();
        bf16_8 af[4], bfr[4];
#pragma unroll
        for (int m = 0; m < 4; ++m) af[m]  = *(const bf16_8*)(&As[wm + m*16 + l16][lg*8]);
#pragma unroll
        for (int n = 0; n < 4; ++n) bfr[n] = *(const bf16_8*)(&Bs[wn + n*16 + l16][lg*8]);
#pragma unroll
        for (int m = 0; m < 4; ++m)
#pragma unroll
            for (int n = 0; n < 4; ++n)
                acc[m][n] = __builtin_amdgcn_mfma_f32_16x16x32_bf16(af[m], bfr[n], acc[m][n], 0, 0, 0);
    }

#pragma unroll
    for (int m = 0; m < 4; ++m) {
#pragma unroll
        for (int n = 0; n < 4; ++n) {
            int col = bn + wn + n*16 + l16;
            float bv = bias[col];
#pragma unroll
            for (int r = 0; r < 4; ++r) {
                int row = bm + wm + m*16 + lg*4 + r;   // C/D: col=lane&15, row=(lane>>4)*4+reg
                float v = acc[m][n][r] + bv;
                if (ADD_RES) v += res[(size_t)row * N + col];
                if (RELU)    v = fmaxf(v, 0.f);
                if (OUT_BF16) ((unsigned short*)Cout)[(size_t)row * N + col] = f2bf(v);
                else          ((float*)Cout)[(size_t)row * N + col] = v;
            }
        }
    }
}

// ---------------- Flash attention: 4 waves x 16 q-rows, KV tile 64 ----------
template<bool CAUSAL>
__global__ __launch_bounds__(256) void k_attn(
        const unsigned short* __restrict__ Qp,
        const unsigned short* __restrict__ Kp,
        const unsigned short* __restrict__ Vp,
        unsigned short* __restrict__ Yp,
        int strideQ, int strideKV, float scale) {
    __shared__ unsigned short Ks[64][72];      // K tile row-major [kpos][d]
    __shared__ unsigned short Vt[64][72];      // V tile transposed [d][kpos]
    __shared__ unsigned short Ps[4][16][72];   // per-wave P tile [qrow][kpos]
    int tid  = threadIdx.x;
    int lane = tid & 63, wave = tid >> 6;
    int l16 = lane & 15, lg = lane >> 4;
    int bh = blockIdx.y;
    int b = bh / NHEAD, h = bh - b * NHEAD;
    int qt = blockIdx.x;
    int wq = qt * 64 + wave * 16;              // this wave's q strip start (in T)

    const unsigned short* Qb = Qp + (size_t)b * TB * strideQ  + h * HD;
    const unsigned short* Kb = Kp + (size_t)b * TB * strideKV + h * HD;
    const unsigned short* Vb = Vp + (size_t)b * TB * strideKV + h * HD;

    // Q fragments hoisted to registers (A-operand: row=l16, k=lg*8..)
    bf16_8 qf0 = *(const bf16_8*)(Qb + (size_t)(wq + l16) * strideQ + lg * 8);
    bf16_8 qf1 = *(const bf16_8*)(Qb + (size_t)(wq + l16) * strideQ + 32 + lg * 8);

    f32x4 o[4] = {};
    float m_run[4], l_run[4];
#pragma unroll
    for (int r = 0; r < 4; ++r) { m_run[r] = -1e30f; l_run[r] = 0.f; }

    int ktEnd = CAUSAL ? (qt + 1) : (TB / 64);
    for (int kt = 0; kt < ktEnd; ++kt) {
        __syncthreads();
#pragma unroll
        for (int i = 0; i < 2; ++i) {
            int chunk = tid + i * 256;         // 512 chunks of 8
            int r = chunk >> 3, cc = (chunk & 7) * 8;
            *(int4*)(&Ks[r][cc]) = *(const int4*)(Kb + (size_t)(kt*64 + r) * strideKV + cc);
            int4 w = *(const int4*)(Vb + (size_t)(kt*64 + r) * strideKV + cc);
            unsigned short* wsp = (unsigned short*)&w;
#pragma unroll
            for (int j = 0; j < 8; ++j) Vt[cc + j][r] = wsp[j];
        }
        __syncthreads();

        // S = Q K^T  (per wave 16 x 64)
        f32x4 s[4];
#pragma unroll
        for (int n = 0; n < 4; ++n) {
            f32x4 z = {};
            bf16_8 kf0 = *(const bf16_8*)(&Ks[n*16 + l16][lg*8]);
            bf16_8 kf1 = *(const bf16_8*)(&Ks[n*16 + l16][32 + lg*8]);
            z = __builtin_amdgcn_mfma_f32_16x16x32_bf16(qf0, kf0, z, 0, 0, 0);
            z = __builtin_amdgcn_mfma_f32_16x16x32_bf16(qf1, kf1, z, 0, 0, 0);
            s[n] = z;
        }
        // scale + causal mask
#pragma unroll
        for (int n = 0; n < 4; ++n)
#pragma unroll
            for (int r = 0; r < 4; ++r) {
                float v = s[n][r] * scale;
                if (CAUSAL) {
                    int kpos = kt*64 + n*16 + l16;
                    int qpos = wq + lg*4 + r;
                    if (kpos > qpos) v = -1e30f;
                }
                s[n][r] = v;
            }
        // online softmax (rows live across 16 lanes: butterfly over l&15)
        float mx[4];
#pragma unroll
        for (int r = 0; r < 4; ++r)
            mx[r] = fmaxf(fmaxf(s[0][r], s[1][r]), fmaxf(s[2][r], s[3][r]));
#pragma unroll
        for (int off = 1; off < 16; off <<= 1)
#pragma unroll
            for (int r = 0; r < 4; ++r)
                mx[r] = fmaxf(mx[r], __shfl_xor(mx[r], off, 64));
        float sf[4];
#pragma unroll
        for (int r = 0; r < 4; ++r) {
            float mnew = fmaxf(m_run[r], mx[r]);
            sf[r] = __expf(m_run[r] - mnew);
            m_run[r] = mnew;
        }
        float ps[4] = {0.f, 0.f, 0.f, 0.f};
#pragma unroll
        for (int n = 0; n < 4; ++n)
#pragma unroll
            for (int r = 0; r < 4; ++r) {
                float p = __expf(s[n][r] - m_run[r]);
                s[n][r] = p;
                ps[r] += p;
            }
#pragma unroll
        for (int off = 1; off < 16; off <<= 1)
#pragma unroll
            for (int r = 0; r < 4; ++r)
                ps[r] += __shfl_xor(ps[r], off, 64);
#pragma unroll
        for (int r = 0; r < 4; ++r) l_run[r] = l_run[r] * sf[r] + ps[r];
#pragma unroll
        for (int n = 0; n < 4; ++n)
#pragma unroll
            for (int r = 0; r < 4; ++r) o[n][r] *= sf[r];

        // P -> LDS (bf16) so we can re-fragment as MFMA A-operand
#pragma unroll
        for (int n = 0; n < 4; ++n)
#pragma unroll
            for (int r = 0; r < 4; ++r)
                Ps[wave][lg*4 + r][n*16 + l16] = f2bf(s[n][r]);
        __syncthreads();   // uniform; also orders Ps write->read

        // O += P @ V
#pragma unroll
        for (int kk = 0; kk < 2; ++kk) {
            bf16_8 pa = *(const bf16_8*)(&Ps[wave][l16][kk*32 + lg*8]);
#pragma unroll
            for (int n = 0; n < 4; ++n) {
                bf16_8 vf = *(const bf16_8*)(&Vt[n*16 + l16][kk*32 + lg*8]);
                o[n] = __builtin_amdgcn_mfma_f32_16x16x32_bf16(pa, vf, o[n], 0, 0, 0);
            }
        }
    }

    // epilogue: O / l -> Y (bf16, [token][h*64+d])
#pragma unroll
    for (int n = 0; n < 4; ++n)
#pragma unroll
        for (int r = 0; r < 4; ++r) {
            int token = b * TB + wq + lg*4 + r;
            float val = o[n][r] / l_run[r];
            Yp[(size_t)token * C_EMBD + h * HD + n*16 + l16] = f2bf(val);
        }
}

// ---------------- LayerNorm over C=768, one block per row ----------------
template<bool WF32, bool WBF16>
__global__ __launch_bounds__(256) void k_ln(const float* __restrict__ in,
                                            const float* __restrict__ g,
                                            const float* __restrict__ bb,
                                            float* __restrict__ outf,
                                            unsigned short* __restrict__ outb) {
    int row = blockIdx.x;
    const float* x = in + (size_t)row * C_EMBD;
    float v[3], s1 = 0.f, s2 = 0.f;
#pragma unroll
    for (int i = 0; i < 3; ++i) {
        v[i] = x[threadIdx.x + i * 256];
        s1 += v[i];
        s2 += v[i] * v[i];
    }
#pragma unroll
    for (int off = 1; off < 64; off <<= 1) {
        s1 += __shfl_xor(s1, off, 64);
        s2 += __shfl_xor(s2, off, 64);
    }
    __shared__ float red[8];
    int wave = threadIdx.x >> 6, lane = threadIdx.x & 63;
    if (lane == 0) { red[wave] = s1; red[4 + wave] = s2; }
    __syncthreads();
    s1 = red[0] + red[1] + red[2] + red[3];
    s2 = red[4] + red[5] + red[6] + red[7];
    float mu  = s1 * (1.f / C_EMBD);
    float var = s2 * (1.f / C_EMBD) - mu * mu;
    float rs  = rsqrtf(var + 1e-5f);
#pragma unroll
    for (int i = 0; i < 3; ++i) {
        int c = threadIdx.x + i * 256;
        float y = (v[i] - mu) * rs * g[c] + bb[c];
        if (WF32)  outf[(size_t)row * C_EMBD + c] = y;
        if (WBF16) outb[(size_t)row * C_EMBD + c] = f2bf(y);
    }
}

// ---------------------------------------------------------------------------
extern "C" void kernel_launch(void* const* d_in, const int* in_sizes, int n_in,
                              void* d_out, int out_size, void* d_ws, size_t ws_size,
                              hipStream_t stream) {
    (void)in_sizes; (void)n_in; (void)out_size; (void)ws_size;
    const float* x      = (const float*)d_in[0];
    const float* enc    = (const float*)d_in[1];
    const float* ln1_g  = (const float*)d_in[2];
    const float* ln1_b  = (const float*)d_in[3];
    const float* qkv_w  = (const float*)d_in[4];
    const float* qkv_b  = (const float*)d_in[5];
    const float* proj_w = (const float*)d_in[6];
    const float* proj_b = (const float*)d_in[7];
    const float* ln2_g  = (const float*)d_in[8];
    const float* ln2_b  = (const float*)d_in[9];
    const float* caq_w  = (const float*)d_in[10];
    const float* caq_b  = (const float*)d_in[11];
    const float* cak_w  = (const float*)d_in[12];
    const float* cak_b  = (const float*)d_in[13];
    const float* cav_w  = (const float*)d_in[14];
    const float* cav_b  = (const float*)d_in[15];
    const float* cao_w  = (const float*)d_in[16];
    const float* cao_b  = (const float*)d_in[17];
    const float* ln3_g  = (const float*)d_in[18];
    const float* ln3_b  = (const float*)d_in[19];
    const float* fc_w   = (const float*)d_in[20];
    const float* fc_b   = (const float*)d_in[21];
    const float* fc2_w  = (const float*)d_in[22];
    const float* fc2_b  = (const float*)d_in[23];
    float* out = (float*)d_out;

    char* ws = (char*)d_ws;
    auto us = [&](size_t off) { return (unsigned short*)(ws + off); };
    auto fl = [&](size_t off) { return (float*)(ws + off); };

    // arena offsets (bytes, all 256-aligned); total 125,829,120 B
    const size_t O_WQKV  = 0;            // 2304x768 bf16
    const size_t O_WPROJ = 3538944;      // 768x768
    const size_t O_WCQ   = 4718592;
    const size_t O_WCK   = 5898240;
    const size_t O_WCV   = 7077888;
    const size_t O_WCO   = 8257536;
    const size_t O_WFC   = 9437184;      // 3072x768
    const size_t O_WFC2  = 14155776;     // 768x3072
    const size_t O_XBF   = 18874368;     // 4096x768 bf16
    const size_t O_ENCBF = 25165824;
    const size_t O_QKVBF = 31457280;     // 4096x2304 bf16 (later cq/ck/cv)
    const size_t O_Q2    = O_QKVBF;
    const size_t O_K2    = O_QKVBF + 6291456;
    const size_t O_V2    = O_QKVBF + 12582912;
    const size_t O_YBF   = 50331648;     // 4096x768 bf16 (attn out, reused)
    const size_t O_RESF  = 56623104;     // 4096x768 f32 (pre-LN, reused 3x)
    const size_t O_X1F   = 69206016;
    const size_t O_X1BF  = 81788928;
    const size_t O_X2F   = 88080384;
    const size_t O_X2BF  = 100663296;
    const size_t O_HBF   = 106954752;    // 4096x3072 bf16

    dim3 tb(32, 8);

    // 1) activations -> bf16
    k_conv_bf16<<<3072, 256, 0, stream>>>(x,   us(O_XBF));
    k_conv_bf16<<<3072, 256, 0, stream>>>(enc, us(O_ENCBF));

    // 2) weights -> bf16 transposed [N][K]
    k_transpose_w<<<dim3(2304/32,  768/32), tb, 0, stream>>>(qkv_w,  us(O_WQKV),  768, 2304);
    k_transpose_w<<<dim3( 768/32,  768/32), tb, 0, stream>>>(proj_w, us(O_WPROJ), 768,  768);
    k_transpose_w<<<dim3( 768/32,  768/32), tb, 0, stream>>>(caq_w,  us(O_WCQ),   768,  768);
    k_transpose_w<<<dim3( 768/32,  768/32), tb, 0, stream>>>(cak_w,  us(O_WCK),   768,  768);
    k_transpose_w<<<dim3( 768/32,  768/32), tb, 0, stream>>>(cav_w,  us(O_WCV),   768,  768);
    k_transpose_w<<<dim3( 768/32,  768/32), tb, 0, stream>>>(cao_w,  us(O_WCO),   768,  768);
    k_transpose_w<<<dim3(3072/32,  768/32), tb, 0, stream>>>(fc_w,   us(O_WFC),   768, 3072);
    k_transpose_w<<<dim3( 768/32, 3072/32), tb, 0, stream>>>(fc2_w,  us(O_WFC2), 3072,  768);

    // 3) qkv = x @ Wqkv + b        (bf16 out)
    k_gemm_bt<true,  false, false><<<dim3(32, 18), 256, 0, stream>>>(
        us(O_XBF), us(O_WQKV), qkv_b, nullptr, us(O_QKVBF), MTOK, 2304, 768);
    // 4) self-attention (causal)
    k_attn<true><<<dim3(TB/64, BB*NHEAD), 256, 0, stream>>>(
        us(O_QKVBF), us(O_QKVBF) + 768, us(O_QKVBF) + 1536, us(O_YBF), 2304, 2304, 0.125f);
    // 5) proj + bias + residual(x) -> fp32
    k_gemm_bt<false, true,  false><<<dim3(32, 6), 256, 0, stream>>>(
        us(O_YBF), us(O_WPROJ), proj_b, x, fl(O_RESF), MTOK, 768, 768);
    // 6) LN1 -> x1 (f32 + bf16)
    k_ln<true, true><<<MTOK, 256, 0, stream>>>(fl(O_RESF), ln1_g, ln1_b, fl(O_X1F), us(O_X1BF));
    // 7) cross-attn projections
    k_gemm_bt<true,  false, false><<<dim3(32, 6), 256, 0, stream>>>(
        us(O_X1BF),  us(O_WCQ), caq_b, nullptr, us(O_Q2), MTOK, 768, 768);
    k_gemm_bt<true,  false, false><<<dim3(32, 6), 256, 0, stream>>>(
        us(O_ENCBF), us(O_WCK), cak_b, nullptr, us(O_K2), MTOK, 768, 768);
    k_gemm_bt<true,  false, false><<<dim3(32, 6), 256, 0, stream>>>(
        us(O_ENCBF), us(O_WCV), cav_b, nullptr, us(O_V2), MTOK, 768, 768);
    // 8) cross-attention (non-causal)
    k_attn<false><<<dim3(TB/64, BB*NHEAD), 256, 0, stream>>>(
        us(O_Q2), us(O_K2), us(O_V2), us(O_YBF), 768, 768, 0.125f);
    // 9) ca_o + bias + residual(x1) -> fp32
    k_gemm_bt<false, true,  false><<<dim3(32, 6), 256, 0, stream>>>(
        us(O_YBF), us(O_WCO), cao_b, fl(O_X1F), fl(O_RESF), MTOK, 768, 768);
    // 10) LN2 -> x2
    k_ln<true, true><<<MTOK, 256, 0, stream>>>(fl(O_RESF), ln2_g, ln2_b, fl(O_X2F), us(O_X2BF));
    // 11) fc + bias + relu -> bf16
    k_gemm_bt<true,  false, true ><<<dim3(32, 24), 256, 0, stream>>>(
        us(O_X2BF), us(O_WFC), fc_b, nullptr, us(O_HBF), MTOK, 3072, 768);
    // 12) fc2 + bias + residual(x2) -> fp32
    k_gemm_bt<false, true,  false><<<dim3(32, 6), 256, 0, stream>>>(
        us(O_HBF), us(O_WFC2), fc2_b, fl(O_X2F), fl(O_RESF), MTOK, 768, 3072);
    // 13) LN3 -> out (fp32 only)
    k_ln<true, false><<<MTOK, 256, 0, stream>>>(fl(O_RESF), ln3_g, ln3_b, out, nullptr);
}

// Round 2
// 611.363 us; speedup vs baseline: 1.1125x; 1.1125x over previous
//
#include <hip/hip_runtime.h>

// ---------------------------------------------------------------------------
// DecoderBlock: B=2, T=2048, C=768, H=12, d=64
// All GEMMs bf16 MFMA (fp32 accum), m97-style global_load_lds staging.
// Attention: flash-style, 4 waves x 16 q-rows, KV tile 64, conflict-free
// packed-b32 V-transpose staging.
// ---------------------------------------------------------------------------

#define C_EMBD 768
#define NHEAD  12
#define HD     64
#define TB     2048
#define BB     2
#define MTOK   (BB*TB)   // 4096 tokens

typedef __bf16 bf16_8 __attribute__((ext_vector_type(8)));
typedef float  f32x4  __attribute__((ext_vector_type(4)));

__device__ __forceinline__ unsigned short f2bf(float f) {
    union { float f; unsigned u; } x; x.f = f;
    unsigned r = x.u + 0x7FFFu + ((x.u >> 16) & 1u);   // RNE
    return (unsigned short)(r >> 16);
}

#define GLOAD_LDS16(gsrc, ldst) \
    __builtin_amdgcn_global_load_lds( \
        (const __attribute__((address_space(1))) void*)(gsrc), \
        (__attribute__((address_space(3))) void*)(ldst), 16, 0, 0)

// ---------------- fp32 -> bf16 convert (4 el/thread) ----------------
__global__ __launch_bounds__(256) void k_conv_bf16(const float* __restrict__ in,
                                                   unsigned short* __restrict__ out) {
    int i = blockIdx.x * 256 + threadIdx.x;
    float4 v = ((const float4*)in)[i];
    ushort4 o;
    o.x = f2bf(v.x); o.y = f2bf(v.y); o.z = f2bf(v.z); o.w = f2bf(v.w);
    ((ushort4*)out)[i] = o;
}

// ------------- W (KxN fp32) -> Wt (NxK bf16) transpose -------------
__global__ __launch_bounds__(256) void k_transpose_w(const float* __restrict__ W,
                                                     unsigned short* __restrict__ Wt,
                                                     int K, int N) {
    __shared__ float tile[32][33];
    int tx = threadIdx.x, ty = threadIdx.y;
    int n0 = blockIdx.x * 32, k0 = blockIdx.y * 32;
#pragma unroll
    for (int i = 0; i < 4; ++i)
        tile[ty + 8*i][tx] = W[(size_t)(k0 + ty + 8*i) * N + n0 + tx];
    __syncthreads();
#pragma unroll
    for (int i = 0; i < 4; ++i)
        Wt[(size_t)(n0 + ty + 8*i) * K + k0 + tx] = f2bf(tile[tx][ty + 8*i]);
}

// ---------------- GEMM: C[MxN] = A[MxK] @ Bt[NxK]^T + bias (+res)(+relu) ----
// m97 structure: 256 thr = 4 waves (2x2), 128x128 tile, BK=32, linear LDS,
// global_load_lds width-16 staging, 16x16x32 bf16 MFMA.
template<bool OUT_BF16, bool ADD_RES, bool RELU>
__global__ __launch_bounds__(256) void k_gemm_bt(
        const unsigned short* __restrict__ A,
        const unsigned short* __restrict__ Bt,
        const float* __restrict__ bias,
        const float* __restrict__ res,
        void* __restrict__ Cout,
        int M, int N, int K) {
    __shared__ unsigned short As[128 * 32];   // linear: row*32 + col
    __shared__ unsigned short Bs[128 * 32];
    int tid  = threadIdx.x;
    int lane = tid & 63, wave = tid >> 6;
    int l16 = lane & 15, lg = lane >> 4;
    int wm = (wave >> 1) * 64, wn = (wave & 1) * 64;
    int bm = blockIdx.x * 128, bn = blockIdx.y * 128;

    f32x4 acc[4][4] = {};

    for (int k0 = 0; k0 < K; k0 += 32) {
        __syncthreads();
#pragma unroll
        for (int i = 0; i < 2; ++i) {
            int chunk = i * 256 + tid;           // 512 chunks of 16B per matrix
            int r = chunk >> 2, cb = (chunk & 3) * 8;
            // wave-uniform LDS base; HW adds lane*16
            unsigned short* la = As + (size_t)(i * 256 + wave * 64) * 8;
            unsigned short* lb = Bs + (size_t)(i * 256 + wave * 64) * 8;
            GLOAD_LDS16(A  + (size_t)(bm + r) * K + k0 + cb, la);
            GLOAD_LDS16(Bt + (size_t)(bn + r) * K + k0 + cb, lb);
        }
        __syncthreads();   // compiler drains vmcnt(0) here -> LDS ready
        bf16_8 af[4], bfr[4];
#pragma unroll
        for (int m = 0; m < 4; ++m)
            af[m]  = *(const bf16_8*)(As + (size_t)(wm + m*16 + l16) * 32 + lg * 8);
#pragma unroll
        for (int n = 0; n < 4; ++n)
            bfr[n] = *(const bf16_8*)(Bs + (size_t)(wn + n*16 + l16) * 32 + lg * 8);
#pragma unroll
        for (int m = 0; m < 4; ++m)
#pragma unroll
            for (int n = 0; n < 4; ++n)
                acc[m][n] = __builtin_amdgcn_mfma_f32_16x16x32_bf16(af[m], bfr[n], acc[m][n], 0, 0, 0);
    }

#pragma unroll
    for (int m = 0; m < 4; ++m) {
#pragma unroll
        for (int n = 0; n < 4; ++n) {
            int col = bn + wn + n*16 + l16;
            float bv = bias[col];
#pragma unroll
            for (int r = 0; r < 4; ++r) {
                int row = bm + wm + m*16 + lg*4 + r;   // C/D: col=lane&15, row=(lane>>4)*4+reg
                float v = acc[m][n][r] + bv;
                if (ADD_RES) v += res[(size_t)row * N + col];
                if (RELU)    v = fmaxf(v, 0.f);
                if (OUT_BF16) ((unsigned short*)Cout)[(size_t)row * N + col] = f2bf(v);
                else          ((float*)Cout)[(size_t)row * N + col] = v;
            }
        }
    }
}

// ---------------- Flash attention: 4 waves x 16 q-rows, KV tile 64 ----------
template<bool CAUSAL>
__global__ __launch_bounds__(256) void k_attn(
        const unsigned short* __restrict__ Qp,
        const unsigned short* __restrict__ Kp,
        const unsigned short* __restrict__ Vp,
        unsigned short* __restrict__ Yp,
        int strideQ, int strideKV, float scale) {
    __shared__ unsigned short Ks[64][72];      // K tile row-major [kpos][d]
    __shared__ unsigned short Vt[64][72];      // V tile transposed [d][kpos]
    __shared__ unsigned short Ps[4][16][72];   // per-wave P tile [qrow][kpos]
    int tid  = threadIdx.x;
    int lane = tid & 63, wave = tid >> 6;
    int l16 = lane & 15, lg = lane >> 4;
    int bh = blockIdx.y;
    int b = bh / NHEAD, h = bh - b * NHEAD;
    int qt = blockIdx.x;
    int wq = qt * 64 + wave * 16;              // this wave's q strip start (in T)

    const unsigned short* Qb = Qp + (size_t)b * TB * strideQ  + h * HD;
    const unsigned short* Kb = Kp + (size_t)b * TB * strideKV + h * HD;
    const unsigned short* Vb = Vp + (size_t)b * TB * strideKV + h * HD;

    // Q fragments hoisted to registers (A-operand: row=l16, k=lg*8..)
    bf16_8 qf0 = *(const bf16_8*)(Qb + (size_t)(wq + l16) * strideQ + lg * 8);
    bf16_8 qf1 = *(const bf16_8*)(Qb + (size_t)(wq + l16) * strideQ + 32 + lg * 8);

    // V-transpose staging assignment: 2 k-rows x 8 d per thread
    int vk2 = (tid & 31) * 2;                  // even k
    int vd0 = (tid >> 5) * 8;                  // d block of 8

    f32x4 o[4] = {};
    float m_run[4], l_run[4];
#pragma unroll
    for (int r = 0; r < 4; ++r) { m_run[r] = -1e30f; l_run[r] = 0.f; }

    int ktEnd = CAUSAL ? (qt + 1) : (TB / 64);
    for (int kt = 0; kt < ktEnd; ++kt) {
        __syncthreads();
        // K tile: vectorized row-major into padded LDS
#pragma unroll
        for (int i = 0; i < 2; ++i) {
            int chunk = tid + i * 256;         // 512 chunks of 8
            int r = chunk >> 3, cc = (chunk & 7) * 8;
            *(int4*)(&Ks[r][cc]) = *(const int4*)(Kb + (size_t)(kt*64 + r) * strideKV + cc);
        }
        // V tile transposed: packed-b32 conflict-free writes
        {
            int4 va = *(const int4*)(Vb + (size_t)(kt*64 + vk2)     * strideKV + vd0);
            int4 vb = *(const int4*)(Vb + (size_t)(kt*64 + vk2 + 1) * strideKV + vd0);
            const unsigned short* pa = (const unsigned short*)&va;
            const unsigned short* pb = (const unsigned short*)&vb;
#pragma unroll
            for (int j = 0; j < 8; ++j) {
                unsigned pack = (unsigned)pa[j] | ((unsigned)pb[j] << 16);
                *(unsigned*)(&Vt[vd0 + j][vk2]) = pack;
            }
        }
        __syncthreads();

        // S = Q K^T  (per wave 16 x 64)
        f32x4 s[4];
#pragma unroll
        for (int n = 0; n < 4; ++n) {
            f32x4 z = {};
            bf16_8 kf0 = *(const bf16_8*)(&Ks[n*16 + l16][lg*8]);
            bf16_8 kf1 = *(const bf16_8*)(&Ks[n*16 + l16][32 + lg*8]);
            z = __builtin_amdgcn_mfma_f32_16x16x32_bf16(qf0, kf0, z, 0, 0, 0);
            z = __builtin_amdgcn_mfma_f32_16x16x32_bf16(qf1, kf1, z, 0, 0, 0);
            s[n] = z;
        }
        // scale + causal mask
#pragma unroll
        for (int n = 0; n < 4; ++n)
#pragma unroll
            for (int r = 0; r < 4; ++r) {
                float v = s[n][r] * scale;
                if (CAUSAL) {
                    int kpos = kt*64 + n*16 + l16;
                    int qpos = wq + lg*4 + r;
                    if (kpos > qpos) v = -1e30f;
                }
                s[n][r] = v;
            }
        // online softmax (rows live across 16 lanes: butterfly over l&15)
        float mx[4];
#pragma unroll
        for (int r = 0; r < 4; ++r)
            mx[r] = fmaxf(fmaxf(s[0][r], s[1][r]), fmaxf(s[2][r], s[3][r]));
#pragma unroll
        for (int off = 1; off < 16; off <<= 1)
#pragma unroll
            for (int r = 0; r < 4; ++r)
                mx[r] = fmaxf(mx[r], __shfl_xor(mx[r], off, 64));
        float sf[4];
#pragma unroll
        for (int r = 0; r < 4; ++r) {
            float mnew = fmaxf(m_run[r], mx[r]);
            sf[r] = __expf(m_run[r] - mnew);
            m_run[r] = mnew;
        }
        float ps[4] = {0.f, 0.f, 0.f, 0.f};
#pragma unroll
        for (int n = 0; n < 4; ++n)
#pragma unroll
            for (int r = 0; r < 4; ++r) {
                float p = __expf(s[n][r] - m_run[r]);
                s[n][r] = p;
                ps[r] += p;
            }
#pragma unroll
        for (int off = 1; off < 16; off <<= 1)
#pragma unroll
            for (int r = 0; r < 4; ++r)
                ps[r] += __shfl_xor(ps[r], off, 64);
#pragma unroll
        for (int r = 0; r < 4; ++r) l_run[r] = l_run[r] * sf[r] + ps[r];
#pragma unroll
        for (int n = 0; n < 4; ++n)
#pragma unroll
            for (int r = 0; r < 4; ++r) o[n][r] *= sf[r];

        // P -> LDS (bf16) so we can re-fragment as MFMA A-operand
#pragma unroll
        for (int n = 0; n < 4; ++n)
#pragma unroll
            for (int r = 0; r < 4; ++r)
                Ps[wave][lg*4 + r][n*16 + l16] = f2bf(s[n][r]);
        __syncthreads();   // uniform; also orders Ps write->read

        // O += P @ V
#pragma unroll
        for (int kk = 0; kk < 2; ++kk) {
            bf16_8 pa = *(const bf16_8*)(&Ps[wave][l16][kk*32 + lg*8]);
#pragma unroll
            for (int n = 0; n < 4; ++n) {
                bf16_8 vf = *(const bf16_8*)(&Vt[n*16 + l16][kk*32 + lg*8]);
                o[n] = __builtin_amdgcn_mfma_f32_16x16x32_bf16(pa, vf, o[n], 0, 0, 0);
            }
        }
    }

    // epilogue: O / l -> Y (bf16, [token][h*64+d])
#pragma unroll
    for (int n = 0; n < 4; ++n)
#pragma unroll
        for (int r = 0; r < 4; ++r) {
            int token = b * TB + wq + lg*4 + r;
            float val = o[n][r] / l_run[r];
            Yp[(size_t)token * C_EMBD + h * HD + n*16 + l16] = f2bf(val);
        }
}

// ---------------- LayerNorm over C=768, one block per row ----------------
template<bool WF32, bool WBF16>
__global__ __launch_bounds__(256) void k_ln(const float* __restrict__ in,
                                            const float* __restrict__ g,
                                            const float* __restrict__ bb,
                                            float* __restrict__ outf,
                                            unsigned short* __restrict__ outb) {
    int row = blockIdx.x;
    const float* x = in + (size_t)row * C_EMBD;
    float v[3], s1 = 0.f, s2 = 0.f;
#pragma unroll
    for (int i = 0; i < 3; ++i) {
        v[i] = x[threadIdx.x + i * 256];
        s1 += v[i];
        s2 += v[i] * v[i];
    }
#pragma unroll
    for (int off = 1; off < 64; off <<= 1) {
        s1 += __shfl_xor(s1, off, 64);
        s2 += __shfl_xor(s2, off, 64);
    }
    __shared__ float red[8];
    int wave = threadIdx.x >> 6, lane = threadIdx.x & 63;
    if (lane == 0) { red[wave] = s1; red[4 + wave] = s2; }
    __syncthreads();
    s1 = red[0] + red[1] + red[2] + red[3];
    s2 = red[4] + red[5] + red[6] + red[7];
    float mu  = s1 * (1.f / C_EMBD);
    float var = s2 * (1.f / C_EMBD) - mu * mu;
    float rs  = rsqrtf(var + 1e-5f);
#pragma unroll
    for (int i = 0; i < 3; ++i) {
        int c = threadIdx.x + i * 256;
        float y = (v[i] - mu) * rs * g[c] + bb[c];
        if (WF32)  outf[(size_t)row * C_EMBD + c] = y;
        if (WBF16) outb[(size_t)row * C_EMBD + c] = f2bf(y);
    }
}

// ---------------------------------------------------------------------------
extern "C" void kernel_launch(void* const* d_in, const int* in_sizes, int n_in,
                              void* d_out, int out_size, void* d_ws, size_t ws_size,
                              hipStream_t stream) {
    (void)in_sizes; (void)n_in; (void)out_size; (void)ws_size;
    const float* x      = (const float*)d_in[0];
    const float* enc    = (const float*)d_in[1];
    const float* ln1_g  = (const float*)d_in[2];
    const float* ln1_b  = (const float*)d_in[3];
    const float* qkv_w  = (const float*)d_in[4];
    const float* qkv_b  = (const float*)d_in[5];
    const float* proj_w = (const float*)d_in[6];
    const float* proj_b = (const float*)d_in[7];
    const float* ln2_g  = (const float*)d_in[8];
    const float* ln2_b  = (const float*)d_in[9];
    const float* caq_w  = (const float*)d_in[10];
    const float* caq_b  = (const float*)d_in[11];
    const float* cak_w  = (const float*)d_in[12];
    const float* cak_b  = (const float*)d_in[13];
    const float* cav_w  = (const float*)d_in[14];
    const float* cav_b  = (const float*)d_in[15];
    const float* cao_w  = (const float*)d_in[16];
    const float* cao_b  = (const float*)d_in[17];
    const float* ln3_g  = (const float*)d_in[18];
    const float* ln3_b  = (const float*)d_in[19];
    const float* fc_w   = (const float*)d_in[20];
    const float* fc_b   = (const float*)d_in[21];
    const float* fc2_w  = (const float*)d_in[22];
    const float* fc2_b  = (const float*)d_in[23];
    float* out = (float*)d_out;

    char* ws = (char*)d_ws;
    auto us = [&](size_t off) { return (unsigned short*)(ws + off); };
    auto fl = [&](size_t off) { return (float*)(ws + off); };

    // arena offsets (bytes, all 256-aligned)
    const size_t O_WQKV  = 0;            // 2304x768 bf16
    const size_t O_WPROJ = 3538944;      // 768x768
    const size_t O_WCQ   = 4718592;
    const size_t O_WCK   = 5898240;
    const size_t O_WCV   = 7077888;
    const size_t O_WCO   = 8257536;
    const size_t O_WFC   = 9437184;      // 3072x768
    const size_t O_WFC2  = 14155776;     // 768x3072
    const size_t O_XBF   = 18874368;     // 4096x768 bf16
    const size_t O_ENCBF = 25165824;
    const size_t O_QKVBF = 31457280;     // 4096x2304 bf16 (later cq/ck/cv)
    const size_t O_Q2    = O_QKVBF;
    const size_t O_K2    = O_QKVBF + 6291456;
    const size_t O_V2    = O_QKVBF + 12582912;
    const size_t O_YBF   = 50331648;     // 4096x768 bf16 (attn out, reused)
    const size_t O_RESF  = 56623104;     // 4096x768 f32 (pre-LN, reused 3x)
    const size_t O_X1F   = 69206016;
    const size_t O_X1BF  = 81788928;
    const size_t O_X2F   = 88080384;
    const size_t O_X2BF  = 100663296;
    const size_t O_HBF   = 106954752;    // 4096x3072 bf16

    dim3 tb(32, 8);

    // 1) activations -> bf16
    k_conv_bf16<<<3072, 256, 0, stream>>>(x,   us(O_XBF));
    k_conv_bf16<<<3072, 256, 0, stream>>>(enc, us(O_ENCBF));

    // 2) weights -> bf16 transposed [N][K]
    k_transpose_w<<<dim3(2304/32,  768/32), tb, 0, stream>>>(qkv_w,  us(O_WQKV),  768, 2304);
    k_transpose_w<<<dim3( 768/32,  768/32), tb, 0, stream>>>(proj_w, us(O_WPROJ), 768,  768);
    k_transpose_w<<<dim3( 768/32,  768/32), tb, 0, stream>>>(caq_w,  us(O_WCQ),   768,  768);
    k_transpose_w<<<dim3( 768/32,  768/32), tb, 0, stream>>>(cak_w,  us(O_WCK),   768,  768);
    k_transpose_w<<<dim3( 768/32,  768/32), tb, 0, stream>>>(cav_w,  us(O_WCV),   768,  768);
    k_transpose_w<<<dim3( 768/32,  768/32), tb, 0, stream>>>(cao_w,  us(O_WCO),   768,  768);
    k_transpose_w<<<dim3(3072/32,  768/32), tb, 0, stream>>>(fc_w,   us(O_WFC),   768, 3072);
    k_transpose_w<<<dim3( 768/32, 3072/32), tb, 0, stream>>>(fc2_w,  us(O_WFC2), 3072,  768);

    // 3) qkv = x @ Wqkv + b        (bf16 out)
    k_gemm_bt<true,  false, false><<<dim3(32, 18), 256, 0, stream>>>(
        us(O_XBF), us(O_WQKV), qkv_b, nullptr, us(O_QKVBF), MTOK, 2304, 768);
    // 4) self-attention (causal)
    k_attn<true><<<dim3(TB/64, BB*NHEAD), 256, 0, stream>>>(
        us(O_QKVBF), us(O_QKVBF) + 768, us(O_QKVBF) + 1536, us(O_YBF), 2304, 2304, 0.125f);
    // 5) proj + bias + residual(x) -> fp32
    k_gemm_bt<false, true,  false><<<dim3(32, 6), 256, 0, stream>>>(
        us(O_YBF), us(O_WPROJ), proj_b, x, fl(O_RESF), MTOK, 768, 768);
    // 6) LN1 -> x1 (f32 + bf16)
    k_ln<true, true><<<MTOK, 256, 0, stream>>>(fl(O_RESF), ln1_g, ln1_b, fl(O_X1F), us(O_X1BF));
    // 7) cross-attn projections
    k_gemm_bt<true,  false, false><<<dim3(32, 6), 256, 0, stream>>>(
        us(O_X1BF),  us(O_WCQ), caq_b, nullptr, us(O_Q2), MTOK, 768, 768);
    k_gemm_bt<true,  false, false><<<dim3(32, 6), 256, 0, stream>>>(
        us(O_ENCBF), us(O_WCK), cak_b, nullptr, us(O_K2), MTOK, 768, 768);
    k_gemm_bt<true,  false, false><<<dim3(32, 6), 256, 0, stream>>>(
        us(O_ENCBF), us(O_WCV), cav_b, nullptr, us(O_V2), MTOK, 768, 768);
    // 8) cross-attention (non-causal)
    k_attn<false><<<dim3(TB/64, BB*NHEAD), 256, 0, stream>>>(
        us(O_Q2), us(O_K2), us(O_V2), us(O_YBF), 768, 768, 0.125f);
    // 9) ca_o + bias + residual(x1) -> fp32
    k_gemm_bt<false, true,  false><<<dim3(32, 6), 256, 0, stream>>>(
        us(O_YBF), us(O_WCO), cao_b, fl(O_X1F), fl(O_RESF), MTOK, 768, 768);
    // 10) LN2 -> x2
    k_ln<true, true><<<MTOK, 256, 0, stream>>>(fl(O_RESF), ln2_g, ln2_b, fl(O_X2F), us(O_X2BF));
    // 11) fc + bias + relu -> bf16
    k_gemm_bt<true,  false, true ><<<dim3(32, 24), 256, 0, stream>>>(
        us(O_X2BF), us(O_WFC), fc_b, nullptr, us(O_HBF), MTOK, 3072, 768);
    // 12) fc2 + bias + residual(x2) -> fp32
    k_gemm_bt<false, true,  false><<<dim3(32, 6), 256, 0, stream>>>(
        us(O_HBF), us(O_WFC2), fc2_b, fl(O_X2F), fl(O_RESF), MTOK, 768, 3072);
    // 13) LN3 -> out (fp32 only)
    k_ln<true, false><<<MTOK, 256, 0, stream>>>(fl(O_RESF), ln3_g, ln3_b, out, nullptr);
}

// Round 3
// 540.205 us; speedup vs baseline: 1.2590x; 1.1317x over previous
//
#include <hip/hip_runtime.h>

// ---------------------------------------------------------------------------
// DecoderBlock: B=2, T=2048, C=768, H=12, d=64
// GEMMs: bf16 MFMA, m97-style global_load_lds staging, BM templated (128/64).
// Attention: flash-style, 4 waves x 16 q-rows, KV tile 64; exp2-domain
// softmax, row-sum via MFMA-with-ones, causal tail-first scheduling.
// ---------------------------------------------------------------------------

#define C_EMBD 768
#define NHEAD  12
#define HD     64
#define TB     2048
#define BB     2
#define MTOK   (BB*TB)   // 4096 tokens

typedef __bf16 bf16_8 __attribute__((ext_vector_type(8)));
typedef float  f32x4  __attribute__((ext_vector_type(4)));

#if __has_builtin(__builtin_amdgcn_exp2f)
#define EXP2(x) __builtin_amdgcn_exp2f(x)
#else
#define EXP2(x) exp2f(x)
#endif

__device__ __forceinline__ unsigned short f2bf(float f) {
    union { float f; unsigned u; } x; x.f = f;
    unsigned r = x.u + 0x7FFFu + ((x.u >> 16) & 1u);   // RNE
    return (unsigned short)(r >> 16);
}

#define GLOAD_LDS16(gsrc, ldst) \
    __builtin_amdgcn_global_load_lds( \
        (const __attribute__((address_space(1))) void*)(gsrc), \
        (__attribute__((address_space(3))) void*)(ldst), 16, 0, 0)

// ---------------- fp32 -> bf16 convert (4 el/thread) ----------------
__global__ __launch_bounds__(256) void k_conv_bf16(const float* __restrict__ in,
                                                   unsigned short* __restrict__ out) {
    int i = blockIdx.x * 256 + threadIdx.x;
    float4 v = ((const float4*)in)[i];
    ushort4 o;
    o.x = f2bf(v.x); o.y = f2bf(v.y); o.z = f2bf(v.z); o.w = f2bf(v.w);
    ((ushort4*)out)[i] = o;
}

// ---------------- concat two 768-float bias vectors ----------------
__global__ __launch_bounds__(256) void k_concat_bias(const float* __restrict__ a,
                                                     const float* __restrict__ b,
                                                     float* __restrict__ dst) {
    int i = blockIdx.x * 256 + threadIdx.x;
    if (i < C_EMBD) { dst[i] = a[i]; dst[C_EMBD + i] = b[i]; }
}

// ------------- W (KxN fp32) -> Wt (NxK bf16) transpose -------------
__global__ __launch_bounds__(256) void k_transpose_w(const float* __restrict__ W,
                                                     unsigned short* __restrict__ Wt,
                                                     int K, int N) {
    __shared__ float tile[32][33];
    int tx = threadIdx.x, ty = threadIdx.y;
    int n0 = blockIdx.x * 32, k0 = blockIdx.y * 32;
#pragma unroll
    for (int i = 0; i < 4; ++i)
        tile[ty + 8*i][tx] = W[(size_t)(k0 + ty + 8*i) * N + n0 + tx];
    __syncthreads();
#pragma unroll
    for (int i = 0; i < 4; ++i)
        Wt[(size_t)(n0 + ty + 8*i) * K + k0 + tx] = f2bf(tile[tx][ty + 8*i]);
}

// ---------------- GEMM: C[MxN] = A[MxK] @ Bt[NxK]^T + bias (+res)(+relu) ----
// 256 thr = 4 waves (2x2), BMx128 tile, BK=32, linear LDS,
// global_load_lds width-16 staging, 16x16x32 bf16 MFMA.
template<int BM, bool OUT_BF16, bool ADD_RES, bool RELU>
__global__ __launch_bounds__(256) void k_gemm_bt(
        const unsigned short* __restrict__ A,
        const unsigned short* __restrict__ Bt,
        const float* __restrict__ bias,
        const float* __restrict__ res,
        void* __restrict__ Cout,
        int M, int N, int K) {
    constexpr int MF = BM / 32;              // m-fragments per wave
    __shared__ unsigned short As[BM * 32];   // linear: row*32 + col
    __shared__ unsigned short Bs[128 * 32];
    int tid  = threadIdx.x;
    int lane = tid & 63, wave = tid >> 6;
    int l16 = lane & 15, lg = lane >> 4;
    int wm = (wave >> 1) * (BM / 2), wn = (wave & 1) * 64;
    int bm = blockIdx.x * BM, bn = blockIdx.y * 128;

    f32x4 acc[MF][4] = {};

    for (int k0 = 0; k0 < K; k0 += 32) {
        __syncthreads();
#pragma unroll
        for (int i = 0; i < BM / 64; ++i) {
            int chunk = i * 256 + tid;
            GLOAD_LDS16(A + (size_t)(bm + (chunk >> 2)) * K + k0 + (chunk & 3) * 8,
                        As + (size_t)(i * 256 + wave * 64) * 8);
        }
#pragma unroll
        for (int i = 0; i < 2; ++i) {
            int chunk = i * 256 + tid;
            GLOAD_LDS16(Bt + (size_t)(bn + (chunk >> 2)) * K + k0 + (chunk & 3) * 8,
                        Bs + (size_t)(i * 256 + wave * 64) * 8);
        }
        __syncthreads();   // drains vmcnt(0) -> LDS ready
        bf16_8 af[MF], bfr[4];
#pragma unroll
        for (int m = 0; m < MF; ++m)
            af[m]  = *(const bf16_8*)(As + (size_t)(wm + m*16 + l16) * 32 + lg * 8);
#pragma unroll
        for (int n = 0; n < 4; ++n)
            bfr[n] = *(const bf16_8*)(Bs + (size_t)(wn + n*16 + l16) * 32 + lg * 8);
#pragma unroll
        for (int m = 0; m < MF; ++m)
#pragma unroll
            for (int n = 0; n < 4; ++n)
                acc[m][n] = __builtin_amdgcn_mfma_f32_16x16x32_bf16(af[m], bfr[n], acc[m][n], 0, 0, 0);
    }

#pragma unroll
    for (int m = 0; m < MF; ++m) {
#pragma unroll
        for (int n = 0; n < 4; ++n) {
            int col = bn + wn + n*16 + l16;
            float bv = bias[col];
#pragma unroll
            for (int r = 0; r < 4; ++r) {
                int row = bm + wm + m*16 + lg*4 + r;   // C/D: col=lane&15, row=(lane>>4)*4+reg
                float v = acc[m][n][r] + bv;
                if (ADD_RES) v += res[(size_t)row * N + col];
                if (RELU)    v = fmaxf(v, 0.f);
                if (OUT_BF16) ((unsigned short*)Cout)[(size_t)row * N + col] = f2bf(v);
                else          ((float*)Cout)[(size_t)row * N + col] = v;
            }
        }
    }
}

// ---------------- Flash attention: 4 waves x 16 q-rows, KV tile 64 ----------
template<bool CAUSAL>
__global__ __launch_bounds__(256) void k_attn(
        const unsigned short* __restrict__ Qp,
        const unsigned short* __restrict__ Kp,
        const unsigned short* __restrict__ Vp,
        unsigned short* __restrict__ Yp,
        int strideQ, int strideKV, float scale2 /* scale * log2(e) */) {
    __shared__ unsigned short Ks[64][72];      // K tile row-major [kpos][d]
    __shared__ unsigned short Vt[64][72];      // V tile transposed [d][kpos]
    __shared__ unsigned short Ps[4][16][72];   // per-wave P tile [qrow][kpos]
    int tid  = threadIdx.x;
    int lane = tid & 63, wave = tid >> 6;
    int l16 = lane & 15, lg = lane >> 4;
    int bh = blockIdx.y;
    int b = bh / NHEAD, h = bh - b * NHEAD;
    // causal: heaviest q-tiles first (tail-balance)
    int qt = CAUSAL ? (gridDim.x - 1 - blockIdx.x) : blockIdx.x;
    int wq = qt * 64 + wave * 16;              // this wave's q strip start (in T)

    const unsigned short* Qb = Qp + (size_t)b * TB * strideQ  + h * HD;
    const unsigned short* Kb = Kp + (size_t)b * TB * strideKV + h * HD;
    const unsigned short* Vb = Vp + (size_t)b * TB * strideKV + h * HD;

    // Q fragments hoisted to registers (A-operand: row=l16, k=lg*8..)
    bf16_8 qf0 = *(const bf16_8*)(Qb + (size_t)(wq + l16) * strideQ + lg * 8);
    bf16_8 qf1 = *(const bf16_8*)(Qb + (size_t)(wq + l16) * strideQ + 32 + lg * 8);

    // all-ones B fragment: row-sum of P via MFMA (replaces shuffle butterfly)
    bf16_8 vones;
#pragma unroll
    for (int j = 0; j < 8; ++j) vones[j] = (__bf16)1.0f;

    // V-transpose staging assignment: 2 k-rows x 8 d per thread
    int vk2 = (tid & 31) * 2;                  // even k
    int vd0 = (tid >> 5) * 8;                  // d block of 8

    f32x4 o[4] = {};
    float m_run[4], l_run[4];                  // m in log2 domain
#pragma unroll
    for (int r = 0; r < 4; ++r) { m_run[r] = -1e30f; l_run[r] = 0.f; }

    int ktEnd = CAUSAL ? (qt + 1) : (TB / 64);
    for (int kt = 0; kt < ktEnd; ++kt) {
        __syncthreads();
        // K tile: vectorized row-major into padded LDS
#pragma unroll
        for (int i = 0; i < 2; ++i) {
            int chunk = tid + i * 256;         // 512 chunks of 8
            int r = chunk >> 3, cc = (chunk & 7) * 8;
            *(int4*)(&Ks[r][cc]) = *(const int4*)(Kb + (size_t)(kt*64 + r) * strideKV + cc);
        }
        // V tile transposed: packed-b32 conflict-free writes
        {
            int4 va = *(const int4*)(Vb + (size_t)(kt*64 + vk2)     * strideKV + vd0);
            int4 vb = *(const int4*)(Vb + (size_t)(kt*64 + vk2 + 1) * strideKV + vd0);
            const unsigned short* pa = (const unsigned short*)&va;
            const unsigned short* pb = (const unsigned short*)&vb;
#pragma unroll
            for (int j = 0; j < 8; ++j) {
                unsigned pack = (unsigned)pa[j] | ((unsigned)pb[j] << 16);
                *(unsigned*)(&Vt[vd0 + j][vk2]) = pack;
            }
        }
        __syncthreads();

        // S = Q K^T  (per wave 16 x 64), scaled into log2 domain
        f32x4 s[4];
#pragma unroll
        for (int n = 0; n < 4; ++n) {
            f32x4 z = {};
            bf16_8 kf0 = *(const bf16_8*)(&Ks[n*16 + l16][lg*8]);
            bf16_8 kf1 = *(const bf16_8*)(&Ks[n*16 + l16][32 + lg*8]);
            z = __builtin_amdgcn_mfma_f32_16x16x32_bf16(qf0, kf0, z, 0, 0, 0);
            z = __builtin_amdgcn_mfma_f32_16x16x32_bf16(qf1, kf1, z, 0, 0, 0);
            s[n] = z;
        }
#pragma unroll
        for (int n = 0; n < 4; ++n)
#pragma unroll
            for (int r = 0; r < 4; ++r) {
                float v = s[n][r] * scale2;
                if (CAUSAL) {
                    int kpos = kt*64 + n*16 + l16;
                    int qpos = wq + lg*4 + r;
                    if (kpos > qpos) v = -1e30f;
                }
                s[n][r] = v;
            }
        // online softmax: row max via 16-lane butterfly (rows live on l16)
        float mx[4];
#pragma unroll
        for (int r = 0; r < 4; ++r)
            mx[r] = fmaxf(fmaxf(s[0][r], s[1][r]), fmaxf(s[2][r], s[3][r]));
#pragma unroll
        for (int off = 1; off < 16; off <<= 1)
#pragma unroll
            for (int r = 0; r < 4; ++r)
                mx[r] = fmaxf(mx[r], __shfl_xor(mx[r], off, 64));
        float sf[4];
#pragma unroll
        for (int r = 0; r < 4; ++r) {
            float mnew = fmaxf(m_run[r], mx[r]);
            sf[r] = EXP2(m_run[r] - mnew);
            m_run[r] = mnew;
        }
        // P = 2^(s - m)
#pragma unroll
        for (int n = 0; n < 4; ++n)
#pragma unroll
            for (int r = 0; r < 4; ++r)
                s[n][r] = EXP2(s[n][r] - m_run[r]);
        // rescale running O
#pragma unroll
        for (int n = 0; n < 4; ++n)
#pragma unroll
            for (int r = 0; r < 4; ++r) o[n][r] *= sf[r];

        // P -> LDS (bf16) so we can re-fragment as MFMA A-operand
#pragma unroll
        for (int n = 0; n < 4; ++n)
#pragma unroll
            for (int r = 0; r < 4; ++r)
                Ps[wave][lg*4 + r][n*16 + l16] = f2bf(s[n][r]);
        __syncthreads();   // uniform; also orders Ps write->read

        // O += P @ V ; row-sum of P via ones-MFMA
        f32x4 zsum = {};
#pragma unroll
        for (int kk = 0; kk < 2; ++kk) {
            bf16_8 pa = *(const bf16_8*)(&Ps[wave][l16][kk*32 + lg*8]);
            zsum = __builtin_amdgcn_mfma_f32_16x16x32_bf16(pa, vones, zsum, 0, 0, 0);
#pragma unroll
            for (int n = 0; n < 4; ++n) {
                bf16_8 vf = *(const bf16_8*)(&Vt[n*16 + l16][kk*32 + lg*8]);
                o[n] = __builtin_amdgcn_mfma_f32_16x16x32_bf16(pa, vf, o[n], 0, 0, 0);
            }
        }
#pragma unroll
        for (int r = 0; r < 4; ++r) l_run[r] = l_run[r] * sf[r] + zsum[r];
    }

    // epilogue: O / l -> Y (bf16, [token][h*64+d])
#pragma unroll
    for (int n = 0; n < 4; ++n)
#pragma unroll
        for (int r = 0; r < 4; ++r) {
            int token = b * TB + wq + lg*4 + r;
            float val = o[n][r] / l_run[r];
            Yp[(size_t)token * C_EMBD + h * HD + n*16 + l16] = f2bf(val);
        }
}

// ---------------- LayerNorm over C=768, one block per row ----------------
template<bool WF32, bool WBF16>
__global__ __launch_bounds__(256) void k_ln(const float* __restrict__ in,
                                            const float* __restrict__ g,
                                            const float* __restrict__ bb,
                                            float* __restrict__ outf,
                                            unsigned short* __restrict__ outb) {
    int row = blockIdx.x;
    const float* x = in + (size_t)row * C_EMBD;
    float v[3], s1 = 0.f, s2 = 0.f;
#pragma unroll
    for (int i = 0; i < 3; ++i) {
        v[i] = x[threadIdx.x + i * 256];
        s1 += v[i];
        s2 += v[i] * v[i];
    }
#pragma unroll
    for (int off = 1; off < 64; off <<= 1) {
        s1 += __shfl_xor(s1, off, 64);
        s2 += __shfl_xor(s2, off, 64);
    }
    __shared__ float red[8];
    int wave = threadIdx.x >> 6, lane = threadIdx.x & 63;
    if (lane == 0) { red[wave] = s1; red[4 + wave] = s2; }
    __syncthreads();
    s1 = red[0] + red[1] + red[2] + red[3];
    s2 = red[4] + red[5] + red[6] + red[7];
    float mu  = s1 * (1.f / C_EMBD);
    float var = s2 * (1.f / C_EMBD) - mu * mu;
    float rs  = rsqrtf(var + 1e-5f);
#pragma unroll
    for (int i = 0; i < 3; ++i) {
        int c = threadIdx.x + i * 256;
        float y = (v[i] - mu) * rs * g[c] + bb[c];
        if (WF32)  outf[(size_t)row * C_EMBD + c] = y;
        if (WBF16) outb[(size_t)row * C_EMBD + c] = f2bf(y);
    }
}

// ---------------------------------------------------------------------------
extern "C" void kernel_launch(void* const* d_in, const int* in_sizes, int n_in,
                              void* d_out, int out_size, void* d_ws, size_t ws_size,
                              hipStream_t stream) {
    (void)in_sizes; (void)n_in; (void)out_size; (void)ws_size;
    const float* x      = (const float*)d_in[0];
    const float* enc    = (const float*)d_in[1];
    const float* ln1_g  = (const float*)d_in[2];
    const float* ln1_b  = (const float*)d_in[3];
    const float* qkv_w  = (const float*)d_in[4];
    const float* qkv_b  = (const float*)d_in[5];
    const float* proj_w = (const float*)d_in[6];
    const float* proj_b = (const float*)d_in[7];
    const float* ln2_g  = (const float*)d_in[8];
    const float* ln2_b  = (const float*)d_in[9];
    const float* caq_w  = (const float*)d_in[10];
    const float* caq_b  = (const float*)d_in[11];
    const float* cak_w  = (const float*)d_in[12];
    const float* cak_b  = (const float*)d_in[13];
    const float* cav_w  = (const float*)d_in[14];
    const float* cav_b  = (const float*)d_in[15];
    const float* cao_w  = (const float*)d_in[16];
    const float* cao_b  = (const float*)d_in[17];
    const float* ln3_g  = (const float*)d_in[18];
    const float* ln3_b  = (const float*)d_in[19];
    const float* fc_w   = (const float*)d_in[20];
    const float* fc_b   = (const float*)d_in[21];
    const float* fc2_w  = (const float*)d_in[22];
    const float* fc2_b  = (const float*)d_in[23];
    float* out = (float*)d_out;

    char* ws = (char*)d_ws;
    auto us = [&](size_t off) { return (unsigned short*)(ws + off); };
    auto fl = [&](size_t off) { return (float*)(ws + off); };

    // arena offsets (bytes, all 256-aligned)
    const size_t O_WQKV  = 0;            // 2304x768 bf16
    const size_t O_WPROJ = 3538944;      // 768x768
    const size_t O_WCQ   = 4718592;
    const size_t O_WCK   = 5898240;      // [Wck|Wcv] contiguous -> 1536x768
    const size_t O_WCV   = 7077888;
    const size_t O_WCO   = 8257536;
    const size_t O_WFC   = 9437184;      // 3072x768
    const size_t O_WFC2  = 14155776;     // 768x3072
    const size_t O_XBF   = 18874368;     // 4096x768 bf16
    const size_t O_ENCBF = 25165824;
    const size_t O_QKVBF = 31457280;     // 4096x2304 bf16 (later cq + [ck|cv])
    const size_t O_Q2    = O_QKVBF;
    const size_t O_KV2   = O_QKVBF + 6291456;   // 4096x1536 bf16 combined
    const size_t O_YBF   = 50331648;     // 4096x768 bf16 (attn out, reused)
    const size_t O_RESF  = 56623104;     // 4096x768 f32 (pre-LN, reused 3x)
    const size_t O_X1F   = 69206016;
    const size_t O_X1BF  = 81788928;
    const size_t O_X2F   = 88080384;
    const size_t O_X2BF  = 100663296;
    const size_t O_HBF   = 106954752;    // 4096x3072 bf16 (dead until step 11:
    const size_t O_BKV   = O_HBF;        //  host kv-bias concat here early)

    const float SC2 = 0.125f * 1.44269504f;   // scale * log2(e)
    dim3 tb(32, 8);

    // 1) activations -> bf16 ; kv bias concat (O_HBF region dead until fc)
    k_conv_bf16<<<3072, 256, 0, stream>>>(x,   us(O_XBF));
    k_conv_bf16<<<3072, 256, 0, stream>>>(enc, us(O_ENCBF));
    k_concat_bias<<<3, 256, 0, stream>>>(cak_b, cav_b, fl(O_BKV));

    // 2) weights -> bf16 transposed [N][K]
    k_transpose_w<<<dim3(2304/32,  768/32), tb, 0, stream>>>(qkv_w,  us(O_WQKV),  768, 2304);
    k_transpose_w<<<dim3( 768/32,  768/32), tb, 0, stream>>>(proj_w, us(O_WPROJ), 768,  768);
    k_transpose_w<<<dim3( 768/32,  768/32), tb, 0, stream>>>(caq_w,  us(O_WCQ),   768,  768);
    k_transpose_w<<<dim3( 768/32,  768/32), tb, 0, stream>>>(cak_w,  us(O_WCK),   768,  768);
    k_transpose_w<<<dim3( 768/32,  768/32), tb, 0, stream>>>(cav_w,  us(O_WCV),   768,  768);
    k_transpose_w<<<dim3( 768/32,  768/32), tb, 0, stream>>>(cao_w,  us(O_WCO),   768,  768);
    k_transpose_w<<<dim3(3072/32,  768/32), tb, 0, stream>>>(fc_w,   us(O_WFC),   768, 3072);
    k_transpose_w<<<dim3( 768/32, 3072/32), tb, 0, stream>>>(fc2_w,  us(O_WFC2), 3072,  768);

    // 3) qkv = x @ Wqkv + b        (bf16 out)
    k_gemm_bt<128, true,  false, false><<<dim3(32, 18), 256, 0, stream>>>(
        us(O_XBF), us(O_WQKV), qkv_b, nullptr, us(O_QKVBF), MTOK, 2304, 768);
    // 4) self-attention (causal)
    k_attn<true><<<dim3(TB/64, BB*NHEAD), 256, 0, stream>>>(
        us(O_QKVBF), us(O_QKVBF) + 768, us(O_QKVBF) + 1536, us(O_YBF), 2304, 2304, SC2);
    // 5) proj + bias + residual(x) -> fp32
    k_gemm_bt<64, false, true,  false><<<dim3(64, 6), 256, 0, stream>>>(
        us(O_YBF), us(O_WPROJ), proj_b, x, fl(O_RESF), MTOK, 768, 768);
    // 6) LN1 -> x1 (f32 + bf16)
    k_ln<true, true><<<MTOK, 256, 0, stream>>>(fl(O_RESF), ln1_g, ln1_b, fl(O_X1F), us(O_X1BF));
    // 7) cross-attn projections: cq ; [ck|cv] fused (N=1536)
    k_gemm_bt<64, true,  false, false><<<dim3(64, 6), 256, 0, stream>>>(
        us(O_X1BF),  us(O_WCQ), caq_b, nullptr, us(O_Q2), MTOK, 768, 768);
    k_gemm_bt<128, true,  false, false><<<dim3(32, 12), 256, 0, stream>>>(
        us(O_ENCBF), us(O_WCK), fl(O_BKV), nullptr, us(O_KV2), MTOK, 1536, 768);
    // 8) cross-attention (non-causal): K at col 0, V at col 768, stride 1536
    k_attn<false><<<dim3(TB/64, BB*NHEAD), 256, 0, stream>>>(
        us(O_Q2), us(O_KV2), us(O_KV2) + 768, us(O_YBF), 768, 1536, SC2);
    // 9) ca_o + bias + residual(x1) -> fp32
    k_gemm_bt<64, false, true,  false><<<dim3(64, 6), 256, 0, stream>>>(
        us(O_YBF), us(O_WCO), cao_b, fl(O_X1F), fl(O_RESF), MTOK, 768, 768);
    // 10) LN2 -> x2
    k_ln<true, true><<<MTOK, 256, 0, stream>>>(fl(O_RESF), ln2_g, ln2_b, fl(O_X2F), us(O_X2BF));
    // 11) fc + bias + relu -> bf16
    k_gemm_bt<128, true,  false, true ><<<dim3(32, 24), 256, 0, stream>>>(
        us(O_X2BF), us(O_WFC), fc_b, nullptr, us(O_HBF), MTOK, 3072, 768);
    // 12) fc2 + bias + residual(x2) -> fp32
    k_gemm_bt<64, false, true,  false><<<dim3(64, 6), 256, 0, stream>>>(
        us(O_HBF), us(O_WFC2), fc2_b, fl(O_X2F), fl(O_RESF), MTOK, 768, 3072);
    // 13) LN3 -> out (fp32 only)
    k_ln<true, false><<<MTOK, 256, 0, stream>>>(fl(O_RESF), ln3_g, ln3_b, out, nullptr);
}

// Round 5
// 531.176 us; speedup vs baseline: 1.2804x; 1.0170x over previous
//
#include <hip/hip_runtime.h>

// ---------------------------------------------------------------------------
// DecoderBlock: B=2, T=2048, C=768, H=12, d=64
// GEMMs: bf16 MFMA, m97-style global_load_lds staging, BM templated (128/64).
// Attention: flash-style, 4 waves x 16 q-rows, KV tile 64; scale folded into
// Q-weights (log2 domain), diagonal-only causal mask, native bf16 casts,
// defer-max (T13), async reg-staged K/V prefetch (T14), 2 barriers/tile.
// ---------------------------------------------------------------------------

#define C_EMBD 768
#define NHEAD  12
#define HD     64
#define TB     2048
#define BB     2
#define MTOK   (BB*TB)   // 4096 tokens

typedef __bf16 bf16_8 __attribute__((ext_vector_type(8)));
typedef float  f32x4  __attribute__((ext_vector_type(4)));

#define EXP2(x) exp2f(x)

__device__ __forceinline__ unsigned short f2bf(float f) {
    union { __bf16 h; unsigned short u; } c;
    c.h = (__bf16)f;            // compiler lowers to packed cvt (RNE)
    return c.u;
}

#define GLOAD_LDS16(gsrc, ldst) \
    __builtin_amdgcn_global_load_lds( \
        (const __attribute__((address_space(1))) void*)(gsrc), \
        (__attribute__((address_space(3))) void*)(ldst), 16, 0, 0)

// ---------------- fp32 -> bf16 convert (4 el/thread) ----------------
__global__ __launch_bounds__(256) void k_conv_bf16(const float* __restrict__ in,
                                                   unsigned short* __restrict__ out) {
    int i = blockIdx.x * 256 + threadIdx.x;
    float4 v = ((const float4*)in)[i];
    ushort4 o;
    o.x = f2bf(v.x); o.y = f2bf(v.y); o.z = f2bf(v.z); o.w = f2bf(v.w);
    ((ushort4*)out)[i] = o;
}

// ---------------- concat two 768-float bias vectors ----------------
__global__ __launch_bounds__(256) void k_concat_bias(const float* __restrict__ a,
                                                     const float* __restrict__ b,
                                                     float* __restrict__ dst) {
    int i = blockIdx.x * 256 + threadIdx.x;
    if (i < C_EMBD) { dst[i] = a[i]; dst[C_EMBD + i] = b[i]; }
}

// ---------------- scaled bias copy: dst[i] = b[i] * (i<lim ? s : 1) --------
__global__ __launch_bounds__(256) void k_scale_bias(const float* __restrict__ b,
                                                    float* __restrict__ dst,
                                                    int n, float s, int lim) {
    int i = blockIdx.x * 256 + threadIdx.x;
    if (i < n) dst[i] = b[i] * (i < lim ? s : 1.0f);
}

// ------------- W (KxN fp32) -> Wt (NxK bf16) transpose (+row scale) --------
__global__ __launch_bounds__(256) void k_transpose_w(const float* __restrict__ W,
                                                     unsigned short* __restrict__ Wt,
                                                     int K, int N,
                                                     float scale, int scaleLim) {
    __shared__ float tile[32][33];
    int tx = threadIdx.x, ty = threadIdx.y;
    int n0 = blockIdx.x * 32, k0 = blockIdx.y * 32;
#pragma unroll
    for (int i = 0; i < 4; ++i)
        tile[ty + 8*i][tx] = W[(size_t)(k0 + ty + 8*i) * N + n0 + tx];
    __syncthreads();
#pragma unroll
    for (int i = 0; i < 4; ++i) {
        int nrow = n0 + ty + 8*i;
        float s = (nrow < scaleLim) ? scale : 1.0f;
        Wt[(size_t)nrow * K + k0 + tx] = f2bf(tile[tx][ty + 8*i] * s);
    }
}

// ---------------- GEMM: C[MxN] = A[MxK] @ Bt[NxK]^T + bias (+res)(+relu) ----
// 256 thr = 4 waves (2x2), BMx128 tile, BK=32, linear LDS,
// global_load_lds width-16 staging, 16x16x32 bf16 MFMA.
template<int BM, bool OUT_BF16, bool ADD_RES, bool RELU>
__global__ __launch_bounds__(256) void k_gemm_bt(
        const unsigned short* __restrict__ A,
        const unsigned short* __restrict__ Bt,
        const float* __restrict__ bias,
        const float* __restrict__ res,
        void* __restrict__ Cout,
        int M, int N, int K) {
    constexpr int MF = BM / 32;              // m-fragments per wave
    __shared__ unsigned short As[BM * 32];   // linear: row*32 + col
    __shared__ unsigned short Bs[128 * 32];
    int tid  = threadIdx.x;
    int lane = tid & 63, wave = tid >> 6;
    int l16 = lane & 15, lg = lane >> 4;
    int wm = (wave >> 1) * (BM / 2), wn = (wave & 1) * 64;
    int bm = blockIdx.x * BM, bn = blockIdx.y * 128;

    f32x4 acc[MF][4] = {};

    for (int k0 = 0; k0 < K; k0 += 32) {
        __syncthreads();
#pragma unroll
        for (int i = 0; i < BM / 64; ++i) {
            int chunk = i * 256 + tid;
            GLOAD_LDS16(A + (size_t)(bm + (chunk >> 2)) * K + k0 + (chunk & 3) * 8,
                        As + (size_t)(i * 256 + wave * 64) * 8);
        }
#pragma unroll
        for (int i = 0; i < 2; ++i) {
            int chunk = i * 256 + tid;
            GLOAD_LDS16(Bt + (size_t)(bn + (chunk >> 2)) * K + k0 + (chunk & 3) * 8,
                        Bs + (size_t)(i * 256 + wave * 64) * 8);
        }
        __syncthreads();   // drains vmcnt(0) -> LDS ready
        bf16_8 af[MF], bfr[4];
#pragma unroll
        for (int m = 0; m < MF; ++m)
            af[m]  = *(const bf16_8*)(As + (size_t)(wm + m*16 + l16) * 32 + lg * 8);
#pragma unroll
        for (int n = 0; n < 4; ++n)
            bfr[n] = *(const bf16_8*)(Bs + (size_t)(wn + n*16 + l16) * 32 + lg * 8);
#pragma unroll
        for (int m = 0; m < MF; ++m)
#pragma unroll
            for (int n = 0; n < 4; ++n)
                acc[m][n] = __builtin_amdgcn_mfma_f32_16x16x32_bf16(af[m], bfr[n], acc[m][n], 0, 0, 0);
    }

#pragma unroll
    for (int m = 0; m < MF; ++m) {
#pragma unroll
        for (int n = 0; n < 4; ++n) {
            int col = bn + wn + n*16 + l16;
            float bv = bias[col];
#pragma unroll
            for (int r = 0; r < 4; ++r) {
                int row = bm + wm + m*16 + lg*4 + r;   // C/D: col=lane&15, row=(lane>>4)*4+reg
                float v = acc[m][n][r] + bv;
                if (ADD_RES) v += res[(size_t)row * N + col];
                if (RELU)    v = fmaxf(v, 0.f);
                if (OUT_BF16) ((unsigned short*)Cout)[(size_t)row * N + col] = f2bf(v);
                else          ((float*)Cout)[(size_t)row * N + col] = v;
            }
        }
    }
}

// ---------------- Flash attention: 4 waves x 16 q-rows, KV tile 64 ----------
// Q pre-scaled by 0.125*log2(e) (folded into weights) -> softmax in exp2 domain.
template<bool CAUSAL>
__global__ __launch_bounds__(256) void k_attn(
        const unsigned short* __restrict__ Qp,
        const unsigned short* __restrict__ Kp,
        const unsigned short* __restrict__ Vp,
        unsigned short* __restrict__ Yp,
        int strideQ, int strideKV) {
    __shared__ __bf16 Ks[64][72];      // K tile row-major [kpos][d]
    __shared__ __bf16 Vt[64][72];      // V tile transposed [d][kpos]
    __shared__ __bf16 Ps[4][16][72];   // per-wave P tile [qrow][kpos] (wave-private)
    int tid  = threadIdx.x;
    int lane = tid & 63, wave = tid >> 6;
    int l16 = lane & 15, lg = lane >> 4;
    int bh = blockIdx.y;
    int b = bh / NHEAD, h = bh - b * NHEAD;
    // causal: heaviest q-tiles first (tail-balance)
    int qt = CAUSAL ? (gridDim.x - 1 - blockIdx.x) : blockIdx.x;
    int wq = qt * 64 + wave * 16;              // this wave's q strip start (in T)

    const unsigned short* Qb = Qp + (size_t)b * TB * strideQ  + h * HD;
    const unsigned short* Kb = Kp + (size_t)b * TB * strideKV + h * HD;
    const unsigned short* Vb = Vp + (size_t)b * TB * strideKV + h * HD;

    // Q fragments hoisted to registers (A-operand: row=l16, k=lg*8..)
    bf16_8 qf0 = *(const bf16_8*)(Qb + (size_t)(wq + l16) * strideQ + lg * 8);
    bf16_8 qf1 = *(const bf16_8*)(Qb + (size_t)(wq + l16) * strideQ + 32 + lg * 8);

    // all-ones B fragment: row-sum of P via MFMA
    bf16_8 vones;
#pragma unroll
    for (int j = 0; j < 8; ++j) vones[j] = (__bf16)1.0f;

    // staging assignments (constant per thread)
    int kr = tid >> 3, kc = (tid & 7) * 8;     // K: rows kr, kr+32; 8 cols at kc
    int vk2 = (tid & 31) * 2;                  // V: even k row pair
    int vd0 = (tid >> 5) * 8;                  // V: d block of 8

    const unsigned short* gK0 = Kb + (size_t)kr  * strideKV + kc;
    const unsigned short* gK1 = gK0 + (size_t)32 * strideKV;
    const unsigned short* gV0 = Vb + (size_t)vk2 * strideKV + vd0;
    const unsigned short* gV1 = gV0 + strideKV;
    const size_t stepKV = (size_t)64 * strideKV;

    // prologue: load tile 0 into registers (V pre-packed for transposed store)
    int4 kA = *(const int4*)gK0;
    int4 kB = *(const int4*)gK1;
    unsigned vp[8];
    {
        int4 va = *(const int4*)gV0, vb2 = *(const int4*)gV1;
        const unsigned short* pa = (const unsigned short*)&va;
        const unsigned short* pb = (const unsigned short*)&vb2;
#pragma unroll
        for (int j = 0; j < 8; ++j) vp[j] = (unsigned)pa[j] | ((unsigned)pb[j] << 16);
    }

    f32x4 o[4] = {};
    float m_run[4], l_run[4];                  // log2 domain
#pragma unroll
    for (int r = 0; r < 4; ++r) { m_run[r] = -1e30f; l_run[r] = 0.f; }

    int ktEnd = CAUSAL ? (qt + 1) : (TB / 64);
    for (int kt = 0; kt < ktEnd; ++kt) {
        __syncthreads();                       // prev-tile LDS reads done
        *(int4*)(&Ks[kr][kc])      = kA;
        *(int4*)(&Ks[kr + 32][kc]) = kB;
#pragma unroll
        for (int j = 0; j < 8; ++j)
            *(unsigned*)(&Vt[vd0 + j][vk2]) = vp[j];
        __syncthreads();                       // LDS ready

        // T14: issue next tile's global loads now; latency hides under compute
        if (kt + 1 < ktEnd) {
            gK0 += stepKV; gK1 += stepKV; gV0 += stepKV; gV1 += stepKV;
            kA = *(const int4*)gK0;
            kB = *(const int4*)gK1;
            int4 va = *(const int4*)gV0, vb2 = *(const int4*)gV1;
            const unsigned short* pa = (const unsigned short*)&va;
            const unsigned short* pb = (const unsigned short*)&vb2;
#pragma unroll
            for (int j = 0; j < 8; ++j) vp[j] = (unsigned)pa[j] | ((unsigned)pb[j] << 16);
        }

        // S = Q K^T  (per wave 16 x 64), already in log2 domain
        f32x4 s[4];
#pragma unroll
        for (int n = 0; n < 4; ++n) {
            f32x4 z = {};
            bf16_8 kf0 = *(const bf16_8*)(&Ks[n*16 + l16][lg*8]);
            bf16_8 kf1 = *(const bf16_8*)(&Ks[n*16 + l16][32 + lg*8]);
            z = __builtin_amdgcn_mfma_f32_16x16x32_bf16(qf0, kf0, z, 0, 0, 0);
            z = __builtin_amdgcn_mfma_f32_16x16x32_bf16(qf1, kf1, z, 0, 0, 0);
            s[n] = z;
        }
        // causal mask: only the diagonal tile needs it
        if (CAUSAL && kt == qt) {
#pragma unroll
            for (int n = 0; n < 4; ++n)
#pragma unroll
                for (int r = 0; r < 4; ++r)
                    if (kt*64 + n*16 + l16 > wq + lg*4 + r) s[n][r] = -1e30f;
        }
        // row max (rows live on l16-butterfly)
        float mx[4];
#pragma unroll
        for (int r = 0; r < 4; ++r)
            mx[r] = fmaxf(fmaxf(s[0][r], s[1][r]), fmaxf(s[2][r], s[3][r]));
#pragma unroll
        for (int off = 1; off < 16; off <<= 1)
#pragma unroll
            for (int r = 0; r < 4; ++r)
                mx[r] = fmaxf(mx[r], __shfl_xor(mx[r], off, 64));
        // T13 defer-max: rescale only when max grew by > 8 (log2)
        bool big = (mx[0] > m_run[0] + 8.f) | (mx[1] > m_run[1] + 8.f) |
                   (mx[2] > m_run[2] + 8.f) | (mx[3] > m_run[3] + 8.f);
        if (__any(big)) {
#pragma unroll
            for (int r = 0; r < 4; ++r) {
                float mnew = fmaxf(m_run[r], mx[r]);
                float sf = EXP2(m_run[r] - mnew);
                m_run[r] = mnew;
                l_run[r] *= sf;
#pragma unroll
                for (int n = 0; n < 4; ++n) o[n][r] *= sf;
            }
        }
        // P = 2^(s - m) -> LDS bf16 (wave-private: no barrier, lgkmcnt orders)
#pragma unroll
        for (int n = 0; n < 4; ++n)
#pragma unroll
            for (int r = 0; r < 4; ++r)
                Ps[wave][lg*4 + r][n*16 + l16] = (__bf16)EXP2(s[n][r] - m_run[r]);

        // O += P @ V ; row-sum of P via ones-MFMA
        f32x4 zsum = {};
#pragma unroll
        for (int kk = 0; kk < 2; ++kk) {
            bf16_8 pa = *(const bf16_8*)(&Ps[wave][l16][kk*32 + lg*8]);
            zsum = __builtin_amdgcn_mfma_f32_16x16x32_bf16(pa, vones, zsum, 0, 0, 0);
#pragma unroll
            for (int n = 0; n < 4; ++n) {
                bf16_8 vf = *(const bf16_8*)(&Vt[n*16 + l16][kk*32 + lg*8]);
                o[n] = __builtin_amdgcn_mfma_f32_16x16x32_bf16(pa, vf, o[n], 0, 0, 0);
            }
        }
#pragma unroll
        for (int r = 0; r < 4; ++r) l_run[r] += zsum[r];
    }

    // epilogue: O / l -> Y (bf16, [token][h*64+d])
#pragma unroll
    for (int r = 0; r < 4; ++r) {
        float rl = 1.0f / l_run[r];
        int token = b * TB + wq + lg*4 + r;
#pragma unroll
        for (int n = 0; n < 4; ++n)
            Yp[(size_t)token * C_EMBD + h * HD + n*16 + l16] = f2bf(o[n][r] * rl);
    }
}

// ---------------- LayerNorm over C=768, one block per row ----------------
template<bool WF32, bool WBF16>
__global__ __launch_bounds__(256) void k_ln(const float* __restrict__ in,
                                            const float* __restrict__ g,
                                            const float* __restrict__ bb,
                                            float* __restrict__ outf,
                                            unsigned short* __restrict__ outb) {
    int row = blockIdx.x;
    const float* x = in + (size_t)row * C_EMBD;
    float v[3], s1 = 0.f, s2 = 0.f;
#pragma unroll
    for (int i = 0; i < 3; ++i) {
        v[i] = x[threadIdx.x + i * 256];
        s1 += v[i];
        s2 += v[i] * v[i];
    }
#pragma unroll
    for (int off = 1; off < 64; off <<= 1) {
        s1 += __shfl_xor(s1, off, 64);
        s2 += __shfl_xor(s2, off, 64);
    }
    __shared__ float red[8];
    int wave = threadIdx.x >> 6, lane = threadIdx.x & 63;
    if (lane == 0) { red[wave] = s1; red[4 + wave] = s2; }
    __syncthreads();
    s1 = red[0] + red[1] + red[2] + red[3];
    s2 = red[4] + red[5] + red[6] + red[7];
    float mu  = s1 * (1.f / C_EMBD);
    float var = s2 * (1.f / C_EMBD) - mu * mu;
    float rs  = rsqrtf(var + 1e-5f);
#pragma unroll
    for (int i = 0; i < 3; ++i) {
        int c = threadIdx.x + i * 256;
        float y = (v[i] - mu) * rs * g[c] + bb[c];
        if (WF32)  outf[(size_t)row * C_EMBD + c] = y;
        if (WBF16) outb[(size_t)row * C_EMBD + c] = f2bf(y);
    }
}

// ---------------------------------------------------------------------------
extern "C" void kernel_launch(void* const* d_in, const int* in_sizes, int n_in,
                              void* d_out, int out_size, void* d_ws, size_t ws_size,
                              hipStream_t stream) {
    (void)in_sizes; (void)n_in; (void)out_size; (void)ws_size;
    const float* x      = (const float*)d_in[0];
    const float* enc    = (const float*)d_in[1];
    const float* ln1_g  = (const float*)d_in[2];
    const float* ln1_b  = (const float*)d_in[3];
    const float* qkv_w  = (const float*)d_in[4];
    const float* qkv_b  = (const float*)d_in[5];
    const float* proj_w = (const float*)d_in[6];
    const float* proj_b = (const float*)d_in[7];
    const float* ln2_g  = (const float*)d_in[8];
    const float* ln2_b  = (const float*)d_in[9];
    const float* caq_w  = (const float*)d_in[10];
    const float* caq_b  = (const float*)d_in[11];
    const float* cak_w  = (const float*)d_in[12];
    const float* cak_b  = (const float*)d_in[13];
    const float* cav_w  = (const float*)d_in[14];
    const float* cav_b  = (const float*)d_in[15];
    const float* cao_w  = (const float*)d_in[16];
    const float* cao_b  = (const float*)d_in[17];
    const float* ln3_g  = (const float*)d_in[18];
    const float* ln3_b  = (const float*)d_in[19];
    const float* fc_w   = (const float*)d_in[20];
    const float* fc_b   = (const float*)d_in[21];
    const float* fc2_w  = (const float*)d_in[22];
    const float* fc2_b  = (const float*)d_in[23];
    float* out = (float*)d_out;

    char* ws = (char*)d_ws;
    auto us = [&](size_t off) { return (unsigned short*)(ws + off); };
    auto fl = [&](size_t off) { return (float*)(ws + off); };

    // arena offsets (bytes, all 256-aligned)
    const size_t O_WQKV  = 0;            // 2304x768 bf16
    const size_t O_WPROJ = 3538944;      // 768x768
    const size_t O_WCQ   = 4718592;
    const size_t O_WCK   = 5898240;      // [Wck|Wcv] contiguous -> 1536x768
    const size_t O_WCV   = 7077888;
    const size_t O_WCO   = 8257536;
    const size_t O_WFC   = 9437184;      // 3072x768
    const size_t O_WFC2  = 14155776;     // 768x3072
    const size_t O_XBF   = 18874368;     // 4096x768 bf16
    const size_t O_ENCBF = 25165824;
    const size_t O_QKVBF = 31457280;     // 4096x2304 bf16 (later cq + [ck|cv])
    const size_t O_Q2    = O_QKVBF;
    const size_t O_KV2   = O_QKVBF + 6291456;   // 4096x1536 bf16 combined
    const size_t O_YBF   = 50331648;     // 4096x768 bf16 (attn out, reused)
    const size_t O_RESF  = 56623104;     // 4096x768 f32 (pre-LN, reused 3x)
    const size_t O_X1F   = 69206016;
    const size_t O_X1BF  = 81788928;
    const size_t O_X2F   = 88080384;
    const size_t O_X2BF  = 100663296;
    const size_t O_HBF   = 106954752;    // 4096x3072 bf16 (dead until step 11;
    const size_t O_BKV   = O_HBF;        //  bias staging lives here early)
    const size_t O_BQKV  = O_HBF + 8192;
    const size_t O_BCQ   = O_HBF + 20480;

    const float SC2 = 0.125f * 1.44269504f;   // scale * log2(e), folded into Q path
    dim3 tb(32, 8);

    // 1) activations -> bf16 ; staged biases (region dead until fc GEMM)
    k_conv_bf16<<<3072, 256, 0, stream>>>(x,   us(O_XBF));
    k_conv_bf16<<<3072, 256, 0, stream>>>(enc, us(O_ENCBF));
    k_concat_bias<<<3, 256, 0, stream>>>(cak_b, cav_b, fl(O_BKV));
    k_scale_bias<<<9, 256, 0, stream>>>(qkv_b, fl(O_BQKV), 2304, SC2, 768);
    k_scale_bias<<<3, 256, 0, stream>>>(caq_b, fl(O_BCQ),   768, SC2, 768);

    // 2) weights -> bf16 transposed [N][K]; Q-rows pre-scaled by SC2
    k_transpose_w<<<dim3(2304/32,  768/32), tb, 0, stream>>>(qkv_w,  us(O_WQKV),  768, 2304, SC2, 768);
    k_transpose_w<<<dim3( 768/32,  768/32), tb, 0, stream>>>(proj_w, us(O_WPROJ), 768,  768, 1.f, 0);
    k_transpose_w<<<dim3( 768/32,  768/32), tb, 0, stream>>>(caq_w,  us(O_WCQ),   768,  768, SC2, 768);
    k_transpose_w<<<dim3( 768/32,  768/32), tb, 0, stream>>>(cak_w,  us(O_WCK),   768,  768, 1.f, 0);
    k_transpose_w<<<dim3( 768/32,  768/32), tb, 0, stream>>>(cav_w,  us(O_WCV),   768,  768, 1.f, 0);
    k_transpose_w<<<dim3( 768/32,  768/32), tb, 0, stream>>>(cao_w,  us(O_WCO),   768,  768, 1.f, 0);
    k_transpose_w<<<dim3(3072/32,  768/32), tb, 0, stream>>>(fc_w,   us(O_WFC),   768, 3072, 1.f, 0);
    k_transpose_w<<<dim3( 768/32, 3072/32), tb, 0, stream>>>(fc2_w,  us(O_WFC2), 3072,  768, 1.f, 0);

    // 3) qkv = x @ Wqkv' + b'      (bf16 out; Q cols pre-scaled)
    k_gemm_bt<128, true,  false, false><<<dim3(32, 18), 256, 0, stream>>>(
        us(O_XBF), us(O_WQKV), fl(O_BQKV), nullptr, us(O_QKVBF), MTOK, 2304, 768);
    // 4) self-attention (causal)
    k_attn<true><<<dim3(TB/64, BB*NHEAD), 256, 0, stream>>>(
        us(O_QKVBF), us(O_QKVBF) + 768, us(O_QKVBF) + 1536, us(O_YBF), 2304, 2304);
    // 5) proj + bias + residual(x) -> fp32
    k_gemm_bt<64, false, true,  false><<<dim3(64, 6), 256, 0, stream>>>(
        us(O_YBF), us(O_WPROJ), proj_b, x, fl(O_RESF), MTOK, 768, 768);
    // 6) LN1 -> x1 (f32 + bf16)
    k_ln<true, true><<<MTOK, 256, 0, stream>>>(fl(O_RESF), ln1_g, ln1_b, fl(O_X1F), us(O_X1BF));
    // 7) cross-attn projections: cq (pre-scaled) ; [ck|cv] fused (N=1536)
    k_gemm_bt<64, true,  false, false><<<dim3(64, 6), 256, 0, stream>>>(
        us(O_X1BF),  us(O_WCQ), fl(O_BCQ), nullptr, us(O_Q2), MTOK, 768, 768);
    k_gemm_bt<128, true,  false, false><<<dim3(32, 12), 256, 0, stream>>>(
        us(O_ENCBF), us(O_WCK), fl(O_BKV), nullptr, us(O_KV2), MTOK, 1536, 768);
    // 8) cross-attention (non-causal): K at col 0, V at col 768, stride 1536
    k_attn<false><<<dim3(TB/64, BB*NHEAD), 256, 0, stream>>>(
        us(O_Q2), us(O_KV2), us(O_KV2) + 768, us(O_YBF), 768, 1536);
    // 9) ca_o + bias + residual(x1) -> fp32
    k_gemm_bt<64, false, true,  false><<<dim3(64, 6), 256, 0, stream>>>(
        us(O_YBF), us(O_WCO), cao_b, fl(O_X1F), fl(O_RESF), MTOK, 768, 768);
    // 10) LN2 -> x2
    k_ln<true, true><<<MTOK, 256, 0, stream>>>(fl(O_RESF), ln2_g, ln2_b, fl(O_X2F), us(O_X2BF));
    // 11) fc + bias + relu -> bf16
    k_gemm_bt<128, true,  false, true ><<<dim3(32, 24), 256, 0, stream>>>(
        us(O_X2BF), us(O_WFC), fc_b, nullptr, us(O_HBF), MTOK, 3072, 768);
    // 12) fc2 + bias + residual(x2) -> fp32
    k_gemm_bt<64, false, true,  false><<<dim3(64, 6), 256, 0, stream>>>(
        us(O_HBF), us(O_WFC2), fc2_b, fl(O_X2F), fl(O_RESF), MTOK, 768, 3072);
    // 13) LN3 -> out (fp32 only)
    k_ln<true, false><<<MTOK, 256, 0, stream>>>(fl(O_RESF), ln3_g, ln3_b, out, nullptr);
}

// Round 6
// 496.760 us; speedup vs baseline: 1.3692x; 1.0693x over previous
//
#include <hip/hip_runtime.h>

// ---------------------------------------------------------------------------
// DecoderBlock: B=2, T=2048, C=768, H=12, d=64
// GEMMs: bf16 MFMA, m97-style global_load_lds staging, BM templated (128/64).
// Attention: flash-style, 4 waves x 16 q-rows, KV tile 64; scale folded into
// Q-weights (log2 domain), diagonal-only causal mask, defer-max (T13),
// reg-staged K/V prefetch (T14). Causal: balanced two-pass (qt pair 31-bx,bx).
// Preprocessing (8 transposes + 2 converts + 3 bias preps) fused in 1 kernel.
// ---------------------------------------------------------------------------

#define C_EMBD 768
#define NHEAD  12
#define HD     64
#define TB     2048
#define BB     2
#define MTOK   (BB*TB)   // 4096 tokens

typedef __bf16 bf16_8 __attribute__((ext_vector_type(8)));
typedef float  f32x4  __attribute__((ext_vector_type(4)));

#define EXP2(x) exp2f(x)

__device__ __forceinline__ unsigned short f2bf(float f) {
    union { __bf16 h; unsigned short u; } c;
    c.h = (__bf16)f;            // packed cvt (RNE)
    return c.u;
}

#define GLOAD_LDS16(gsrc, ldst) \
    __builtin_amdgcn_global_load_lds( \
        (const __attribute__((address_space(1))) void*)(gsrc), \
        (__attribute__((address_space(3))) void*)(ldst), 16, 0, 0)

// ---------------- fused preprocessing ----------------
// blocks [0,9216):   weight transposes (fp32 KxN -> bf16 NxK, optional scale)
// blocks [9216,15360): x/enc fp32 -> bf16
// blocks [15360,15375): bias staging (qkv scaled, kv concat, cq scaled)
__global__ __launch_bounds__(256) void k_preproc(
        const float* __restrict__ x,     const float* __restrict__ enc,
        const float* __restrict__ qkv_w, const float* __restrict__ proj_w,
        const float* __restrict__ caq_w, const float* __restrict__ cak_w,
        const float* __restrict__ cav_w, const float* __restrict__ cao_w,
        const float* __restrict__ fc_w,  const float* __restrict__ fc2_w,
        const float* __restrict__ qkv_b, const float* __restrict__ caq_b,
        const float* __restrict__ cak_b, const float* __restrict__ cav_b,
        unsigned short* __restrict__ xbf,  unsigned short* __restrict__ encbf,
        unsigned short* __restrict__ wqkv, unsigned short* __restrict__ wproj,
        unsigned short* __restrict__ wcq,  unsigned short* __restrict__ wck,
        unsigned short* __restrict__ wcv,  unsigned short* __restrict__ wco,
        unsigned short* __restrict__ wfc,  unsigned short* __restrict__ wfc2,
        float* __restrict__ bqkv, float* __restrict__ bkv, float* __restrict__ bcq,
        float sc2) {
    __shared__ float tile[32][33];
    int b = blockIdx.x, tid = threadIdx.x;
    if (b < 9216) {
        const float* W; unsigned short* Wt; int K, N, t; float sc; int slim;
        if      (b < 1728) { W=qkv_w;  Wt=wqkv;  K=768;  N=2304; t=b;      sc=sc2; slim=768; }
        else if (b < 2304) { W=proj_w; Wt=wproj; K=768;  N=768;  t=b-1728; sc=1.f; slim=0;   }
        else if (b < 2880) { W=caq_w;  Wt=wcq;   K=768;  N=768;  t=b-2304; sc=sc2; slim=768; }
        else if (b < 3456) { W=cak_w;  Wt=wck;   K=768;  N=768;  t=b-2880; sc=1.f; slim=0;   }
        else if (b < 4032) { W=cav_w;  Wt=wcv;   K=768;  N=768;  t=b-3456; sc=1.f; slim=0;   }
        else if (b < 4608) { W=cao_w;  Wt=wco;   K=768;  N=768;  t=b-4032; sc=1.f; slim=0;   }
        else if (b < 6912) { W=fc_w;   Wt=wfc;   K=768;  N=3072; t=b-4608; sc=1.f; slim=0;   }
        else               { W=fc2_w;  Wt=wfc2;  K=3072; N=768;  t=b-6912; sc=1.f; slim=0;   }
        int ntx = N >> 5;
        int n0 = (t % ntx) * 32, k0 = (t / ntx) * 32;
        int tx = tid & 31, ty = tid >> 5;
#pragma unroll
        for (int i = 0; i < 4; ++i)
            tile[ty + 8*i][tx] = W[(size_t)(k0 + ty + 8*i) * N + n0 + tx];
        __syncthreads();
#pragma unroll
        for (int i = 0; i < 4; ++i) {
            int nrow = n0 + ty + 8*i;
            float s = (nrow < slim) ? sc : 1.0f;
            Wt[(size_t)nrow * K + k0 + tx] = f2bf(tile[tx][ty + 8*i] * s);
        }
    } else if (b < 15360) {
        int b2 = b - 9216;
        const float* src = (b2 < 3072) ? x   : enc;
        unsigned short* dst = (b2 < 3072) ? xbf : encbf;
        int i = (b2 < 3072 ? b2 : b2 - 3072) * 256 + tid;
        float4 v = ((const float4*)src)[i];
        ushort4 o;
        o.x = f2bf(v.x); o.y = f2bf(v.y); o.z = f2bf(v.z); o.w = f2bf(v.w);
        ((ushort4*)dst)[i] = o;
    } else {
        int b3 = b - 15360;
        if (b3 < 9) {
            int i = b3 * 256 + tid;
            if (i < 2304) bqkv[i] = qkv_b[i] * (i < 768 ? sc2 : 1.0f);
        } else if (b3 < 12) {
            int i = (b3 - 9) * 256 + tid;
            if (i < 768) { bkv[i] = cak_b[i]; bkv[768 + i] = cav_b[i]; }
        } else {
            int i = (b3 - 12) * 256 + tid;
            if (i < 768) bcq[i] = caq_b[i] * sc2;
        }
    }
}

// ---------------- GEMM: C[MxN] = A[MxK] @ Bt[NxK]^T + bias (+res)(+relu) ----
template<int BM, bool OUT_BF16, bool ADD_RES, bool RELU>
__global__ __launch_bounds__(256) void k_gemm_bt(
        const unsigned short* __restrict__ A,
        const unsigned short* __restrict__ Bt,
        const float* __restrict__ bias,
        const float* __restrict__ res,
        void* __restrict__ Cout,
        int M, int N, int K) {
    constexpr int MF = BM / 32;              // m-fragments per wave
    __shared__ unsigned short As[BM * 32];   // linear: row*32 + col
    __shared__ unsigned short Bs[128 * 32];
    int tid  = threadIdx.x;
    int lane = tid & 63, wave = tid >> 6;
    int l16 = lane & 15, lg = lane >> 4;
    int wm = (wave >> 1) * (BM / 2), wn = (wave & 1) * 64;
    int bm = blockIdx.x * BM, bn = blockIdx.y * 128;

    f32x4 acc[MF][4] = {};

    for (int k0 = 0; k0 < K; k0 += 32) {
        __syncthreads();
#pragma unroll
        for (int i = 0; i < BM / 64; ++i) {
            int chunk = i * 256 + tid;
            GLOAD_LDS16(A + (size_t)(bm + (chunk >> 2)) * K + k0 + (chunk & 3) * 8,
                        As + (size_t)(i * 256 + wave * 64) * 8);
        }
#pragma unroll
        for (int i = 0; i < 2; ++i) {
            int chunk = i * 256 + tid;
            GLOAD_LDS16(Bt + (size_t)(bn + (chunk >> 2)) * K + k0 + (chunk & 3) * 8,
                        Bs + (size_t)(i * 256 + wave * 64) * 8);
        }
        __syncthreads();   // drains vmcnt(0) -> LDS ready
        bf16_8 af[MF], bfr[4];
#pragma unroll
        for (int m = 0; m < MF; ++m)
            af[m]  = *(const bf16_8*)(As + (size_t)(wm + m*16 + l16) * 32 + lg * 8);
#pragma unroll
        for (int n = 0; n < 4; ++n)
            bfr[n] = *(const bf16_8*)(Bs + (size_t)(wn + n*16 + l16) * 32 + lg * 8);
#pragma unroll
        for (int m = 0; m < MF; ++m)
#pragma unroll
            for (int n = 0; n < 4; ++n)
                acc[m][n] = __builtin_amdgcn_mfma_f32_16x16x32_bf16(af[m], bfr[n], acc[m][n], 0, 0, 0);
    }

#pragma unroll
    for (int m = 0; m < MF; ++m) {
#pragma unroll
        for (int n = 0; n < 4; ++n) {
            int col = bn + wn + n*16 + l16;
            float bv = bias[col];
#pragma unroll
            for (int r = 0; r < 4; ++r) {
                int row = bm + wm + m*16 + lg*4 + r;   // C/D: col=lane&15, row=(lane>>4)*4+reg
                float v = acc[m][n][r] + bv;
                if (ADD_RES) v += res[(size_t)row * N + col];
                if (RELU)    v = fmaxf(v, 0.f);
                if (OUT_BF16) ((unsigned short*)Cout)[(size_t)row * N + col] = f2bf(v);
                else          ((float*)Cout)[(size_t)row * N + col] = v;
            }
        }
    }
}

// ---------------- Flash attention: 4 waves x 16 q-rows, KV tile 64 ----------
// Q pre-scaled by 0.125*log2(e). CAUSAL: balanced two-pass, grid.x = 16,
// block bx does q-tile (31-bx) then (bx) -> uniform 34 tile-units per block.
template<bool CAUSAL>
__global__ __launch_bounds__(256) void k_attn(
        const unsigned short* __restrict__ Qp,
        const unsigned short* __restrict__ Kp,
        const unsigned short* __restrict__ Vp,
        unsigned short* __restrict__ Yp,
        int strideQ, int strideKV) {
    __shared__ __bf16 Ks[64][72];      // K tile row-major [kpos][d]
    __shared__ __bf16 Vt[64][72];      // V tile transposed [d][kpos]
    __shared__ __bf16 Ps[4][16][72];   // per-wave P tile (wave-private)
    int tid  = threadIdx.x;
    int lane = tid & 63, wave = tid >> 6;
    int l16 = lane & 15, lg = lane >> 4;
    int bh = blockIdx.y;
    int b = bh / NHEAD, h = bh - b * NHEAD;

    const unsigned short* Qb = Qp + (size_t)b * TB * strideQ  + h * HD;
    const unsigned short* Kb = Kp + (size_t)b * TB * strideKV + h * HD;
    const unsigned short* Vb = Vp + (size_t)b * TB * strideKV + h * HD;

    // all-ones B fragment: row-sum of P via MFMA
    bf16_8 vones;
#pragma unroll
    for (int j = 0; j < 8; ++j) vones[j] = (__bf16)1.0f;

    // staging assignments (constant per thread)
    int kr = tid >> 3, kc = (tid & 7) * 8;     // K: rows kr, kr+32; 8 cols at kc
    int vk2 = (tid & 31) * 2;                  // V: even k row pair
    int vd0 = (tid >> 5) * 8;                  // V: d block of 8
    const size_t stepKV = (size_t)64 * strideKV;

    const int npass = CAUSAL ? 2 : 1;
    for (int pass = 0; pass < npass; ++pass) {
        int qt = CAUSAL ? (pass == 0 ? (TB/64 - 1 - (int)blockIdx.x) : (int)blockIdx.x)
                        : (int)blockIdx.x;
        int wq = qt * 64 + wave * 16;          // this wave's q strip start

        // Q fragments (A-operand: row=l16, k=lg*8..)
        bf16_8 qf0 = *(const bf16_8*)(Qb + (size_t)(wq + l16) * strideQ + lg * 8);
        bf16_8 qf1 = *(const bf16_8*)(Qb + (size_t)(wq + l16) * strideQ + 32 + lg * 8);

        const unsigned short* gK0 = Kb + (size_t)kr  * strideKV + kc;
        const unsigned short* gK1 = gK0 + (size_t)32 * strideKV;
        const unsigned short* gV0 = Vb + (size_t)vk2 * strideKV + vd0;
        const unsigned short* gV1 = gV0 + strideKV;

        // prologue: tile 0 into registers (V pre-packed for transposed store)
        int4 kA = *(const int4*)gK0;
        int4 kB = *(const int4*)gK1;
        unsigned vp[8];
        {
            int4 va = *(const int4*)gV0, vb2 = *(const int4*)gV1;
            const unsigned short* pa = (const unsigned short*)&va;
            const unsigned short* pb = (const unsigned short*)&vb2;
#pragma unroll
            for (int j = 0; j < 8; ++j) vp[j] = (unsigned)pa[j] | ((unsigned)pb[j] << 16);
        }

        f32x4 o[4] = {};
        float m_run[4], l_run[4];              // log2 domain
#pragma unroll
        for (int r = 0; r < 4; ++r) { m_run[r] = -1e30f; l_run[r] = 0.f; }

        int ktEnd = CAUSAL ? (qt + 1) : (TB / 64);
        for (int kt = 0; kt < ktEnd; ++kt) {
            __syncthreads();                   // prev-tile LDS reads done
            *(int4*)(&Ks[kr][kc])      = kA;
            *(int4*)(&Ks[kr + 32][kc]) = kB;
#pragma unroll
            for (int j = 0; j < 8; ++j)
                *(unsigned*)(&Vt[vd0 + j][vk2]) = vp[j];
            __syncthreads();                   // LDS ready

            // T14: issue next tile's global loads; latency hides under compute
            if (kt + 1 < ktEnd) {
                gK0 += stepKV; gK1 += stepKV; gV0 += stepKV; gV1 += stepKV;
                kA = *(const int4*)gK0;
                kB = *(const int4*)gK1;
                int4 va = *(const int4*)gV0, vb2 = *(const int4*)gV1;
                const unsigned short* pa = (const unsigned short*)&va;
                const unsigned short* pb = (const unsigned short*)&vb2;
#pragma unroll
                for (int j = 0; j < 8; ++j) vp[j] = (unsigned)pa[j] | ((unsigned)pb[j] << 16);
            }

            // S = Q K^T  (16 x 64 per wave), log2 domain
            f32x4 s[4];
#pragma unroll
            for (int n = 0; n < 4; ++n) {
                f32x4 z = {};
                bf16_8 kf0 = *(const bf16_8*)(&Ks[n*16 + l16][lg*8]);
                bf16_8 kf1 = *(const bf16_8*)(&Ks[n*16 + l16][32 + lg*8]);
                z = __builtin_amdgcn_mfma_f32_16x16x32_bf16(qf0, kf0, z, 0, 0, 0);
                z = __builtin_amdgcn_mfma_f32_16x16x32_bf16(qf1, kf1, z, 0, 0, 0);
                s[n] = z;
            }
            // causal mask: only the diagonal tile
            if (CAUSAL && kt == qt) {
#pragma unroll
                for (int n = 0; n < 4; ++n)
#pragma unroll
                    for (int r = 0; r < 4; ++r)
                        if (kt*64 + n*16 + l16 > wq + lg*4 + r) s[n][r] = -1e30f;
            }
            // row max (16-lane butterfly)
            float mx[4];
#pragma unroll
            for (int r = 0; r < 4; ++r)
                mx[r] = fmaxf(fmaxf(s[0][r], s[1][r]), fmaxf(s[2][r], s[3][r]));
#pragma unroll
            for (int off = 1; off < 16; off <<= 1)
#pragma unroll
                for (int r = 0; r < 4; ++r)
                    mx[r] = fmaxf(mx[r], __shfl_xor(mx[r], off, 64));
            // T13 defer-max: rescale only when max grew by > 8 (log2)
            bool big = (mx[0] > m_run[0] + 8.f) | (mx[1] > m_run[1] + 8.f) |
                       (mx[2] > m_run[2] + 8.f) | (mx[3] > m_run[3] + 8.f);
            if (__any(big)) {
#pragma unroll
                for (int r = 0; r < 4; ++r) {
                    float mnew = fmaxf(m_run[r], mx[r]);
                    float sf = EXP2(m_run[r] - mnew);
                    m_run[r] = mnew;
                    l_run[r] *= sf;
#pragma unroll
                    for (int n = 0; n < 4; ++n) o[n][r] *= sf;
                }
            }
            // P = 2^(s - m) -> LDS bf16 (wave-private; lgkmcnt orders)
#pragma unroll
            for (int n = 0; n < 4; ++n)
#pragma unroll
                for (int r = 0; r < 4; ++r)
                    Ps[wave][lg*4 + r][n*16 + l16] = (__bf16)EXP2(s[n][r] - m_run[r]);

            // O += P @ V ; row-sum of P via ones-MFMA
            f32x4 zsum = {};
#pragma unroll
            for (int kk = 0; kk < 2; ++kk) {
                bf16_8 pa = *(const bf16_8*)(&Ps[wave][l16][kk*32 + lg*8]);
                zsum = __builtin_amdgcn_mfma_f32_16x16x32_bf16(pa, vones, zsum, 0, 0, 0);
#pragma unroll
                for (int n = 0; n < 4; ++n) {
                    bf16_8 vf = *(const bf16_8*)(&Vt[n*16 + l16][kk*32 + lg*8]);
                    o[n] = __builtin_amdgcn_mfma_f32_16x16x32_bf16(pa, vf, o[n], 0, 0, 0);
                }
            }
#pragma unroll
            for (int r = 0; r < 4; ++r) l_run[r] += zsum[r];
        }

        // epilogue: O / l -> Y (bf16, [token][h*64+d])
#pragma unroll
        for (int r = 0; r < 4; ++r) {
            float rl = 1.0f / l_run[r];
            int token = b * TB + wq + lg*4 + r;
#pragma unroll
            for (int n = 0; n < 4; ++n)
                Yp[(size_t)token * C_EMBD + h * HD + n*16 + l16] = f2bf(o[n][r] * rl);
        }
    }
}

// ---------------- LayerNorm over C=768, one block per row ----------------
template<bool WF32, bool WBF16>
__global__ __launch_bounds__(256) void k_ln(const float* __restrict__ in,
                                            const float* __restrict__ g,
                                            const float* __restrict__ bb,
                                            float* __restrict__ outf,
                                            unsigned short* __restrict__ outb) {
    int row = blockIdx.x;
    const float* x = in + (size_t)row * C_EMBD;
    float v[3], s1 = 0.f, s2 = 0.f;
#pragma unroll
    for (int i = 0; i < 3; ++i) {
        v[i] = x[threadIdx.x + i * 256];
        s1 += v[i];
        s2 += v[i] * v[i];
    }
#pragma unroll
    for (int off = 1; off < 64; off <<= 1) {
        s1 += __shfl_xor(s1, off, 64);
        s2 += __shfl_xor(s2, off, 64);
    }
    __shared__ float red[8];
    int wave = threadIdx.x >> 6, lane = threadIdx.x & 63;
    if (lane == 0) { red[wave] = s1; red[4 + wave] = s2; }
    __syncthreads();
    s1 = red[0] + red[1] + red[2] + red[3];
    s2 = red[4] + red[5] + red[6] + red[7];
    float mu  = s1 * (1.f / C_EMBD);
    float var = s2 * (1.f / C_EMBD) - mu * mu;
    float rs  = rsqrtf(var + 1e-5f);
#pragma unroll
    for (int i = 0; i < 3; ++i) {
        int c = threadIdx.x + i * 256;
        float y = (v[i] - mu) * rs * g[c] + bb[c];
        if (WF32)  outf[(size_t)row * C_EMBD + c] = y;
        if (WBF16) outb[(size_t)row * C_EMBD + c] = f2bf(y);
    }
}

// ---------------------------------------------------------------------------
extern "C" void kernel_launch(void* const* d_in, const int* in_sizes, int n_in,
                              void* d_out, int out_size, void* d_ws, size_t ws_size,
                              hipStream_t stream) {
    (void)in_sizes; (void)n_in; (void)out_size; (void)ws_size;
    const float* x      = (const float*)d_in[0];
    const float* enc    = (const float*)d_in[1];
    const float* ln1_g  = (const float*)d_in[2];
    const float* ln1_b  = (const float*)d_in[3];
    const float* qkv_w  = (const float*)d_in[4];
    const float* qkv_b  = (const float*)d_in[5];
    const float* proj_w = (const float*)d_in[6];
    const float* proj_b = (const float*)d_in[7];
    const float* ln2_g  = (const float*)d_in[8];
    const float* ln2_b  = (const float*)d_in[9];
    const float* caq_w  = (const float*)d_in[10];
    const float* caq_b  = (const float*)d_in[11];
    const float* cak_w  = (const float*)d_in[12];
    const float* cak_b  = (const float*)d_in[13];
    const float* cav_w  = (const float*)d_in[14];
    const float* cav_b  = (const float*)d_in[15];
    const float* cao_w  = (const float*)d_in[16];
    const float* cao_b  = (const float*)d_in[17];
    const float* ln3_g  = (const float*)d_in[18];
    const float* ln3_b  = (const float*)d_in[19];
    const float* fc_w   = (const float*)d_in[20];
    const float* fc_b   = (const float*)d_in[21];
    const float* fc2_w  = (const float*)d_in[22];
    const float* fc2_b  = (const float*)d_in[23];
    float* out = (float*)d_out;

    char* ws = (char*)d_ws;
    auto us = [&](size_t off) { return (unsigned short*)(ws + off); };
    auto fl = [&](size_t off) { return (float*)(ws + off); };

    // arena offsets (bytes, all 256-aligned)
    const size_t O_WQKV  = 0;            // 2304x768 bf16
    const size_t O_WPROJ = 3538944;      // 768x768
    const size_t O_WCQ   = 4718592;
    const size_t O_WCK   = 5898240;      // [Wck|Wcv] contiguous -> 1536x768
    const size_t O_WCV   = 7077888;
    const size_t O_WCO   = 8257536;
    const size_t O_WFC   = 9437184;      // 3072x768
    const size_t O_WFC2  = 14155776;     // 768x3072
    const size_t O_XBF   = 18874368;     // 4096x768 bf16
    const size_t O_ENCBF = 25165824;
    const size_t O_QKVBF = 31457280;     // 4096x2304 bf16 (later cq + [ck|cv])
    const size_t O_Q2    = O_QKVBF;
    const size_t O_KV2   = O_QKVBF + 6291456;   // 4096x1536 bf16 combined
    const size_t O_YBF   = 50331648;     // 4096x768 bf16 (attn out, reused)
    const size_t O_RESF  = 56623104;     // 4096x768 f32 (pre-LN, reused 3x)
    const size_t O_X1F   = 69206016;
    const size_t O_X1BF  = 81788928;
    const size_t O_X2F   = 88080384;
    const size_t O_X2BF  = 100663296;
    const size_t O_HBF   = 106954752;    // 4096x3072 bf16 (dead until step 11;
    const size_t O_BKV   = O_HBF;        //  bias staging lives here early)
    const size_t O_BQKV  = O_HBF + 8192;
    const size_t O_BCQ   = O_HBF + 20480;

    const float SC2 = 0.125f * 1.44269504f;   // scale * log2(e), folded into Q path

    // 1+2) fused preprocessing: all transposes + converts + bias staging
    k_preproc<<<15375, 256, 0, stream>>>(
        x, enc, qkv_w, proj_w, caq_w, cak_w, cav_w, cao_w, fc_w, fc2_w,
        qkv_b, caq_b, cak_b, cav_b,
        us(O_XBF), us(O_ENCBF),
        us(O_WQKV), us(O_WPROJ), us(O_WCQ), us(O_WCK),
        us(O_WCV), us(O_WCO), us(O_WFC), us(O_WFC2),
        fl(O_BQKV), fl(O_BKV), fl(O_BCQ), SC2);

    // 3) qkv = x @ Wqkv' + b'      (bf16 out; Q cols pre-scaled)
    k_gemm_bt<128, true,  false, false><<<dim3(32, 18), 256, 0, stream>>>(
        us(O_XBF), us(O_WQKV), fl(O_BQKV), nullptr, us(O_QKVBF), MTOK, 2304, 768);
    // 4) self-attention (causal, balanced two-pass: grid.x = 16)
    k_attn<true><<<dim3(TB/128, BB*NHEAD), 256, 0, stream>>>(
        us(O_QKVBF), us(O_QKVBF) + 768, us(O_QKVBF) + 1536, us(O_YBF), 2304, 2304);
    // 5) proj + bias + residual(x) -> fp32
    k_gemm_bt<64, false, true,  false><<<dim3(64, 6), 256, 0, stream>>>(
        us(O_YBF), us(O_WPROJ), proj_b, x, fl(O_RESF), MTOK, 768, 768);
    // 6) LN1 -> x1 (f32 + bf16)
    k_ln<true, true><<<MTOK, 256, 0, stream>>>(fl(O_RESF), ln1_g, ln1_b, fl(O_X1F), us(O_X1BF));
    // 7) cross-attn projections: cq (pre-scaled) ; [ck|cv] fused (N=1536)
    k_gemm_bt<64, true,  false, false><<<dim3(64, 6), 256, 0, stream>>>(
        us(O_X1BF),  us(O_WCQ), fl(O_BCQ), nullptr, us(O_Q2), MTOK, 768, 768);
    k_gemm_bt<128, true,  false, false><<<dim3(32, 12), 256, 0, stream>>>(
        us(O_ENCBF), us(O_WCK), fl(O_BKV), nullptr, us(O_KV2), MTOK, 1536, 768);
    // 8) cross-attention (non-causal): K at col 0, V at col 768, stride 1536
    k_attn<false><<<dim3(TB/64, BB*NHEAD), 256, 0, stream>>>(
        us(O_Q2), us(O_KV2), us(O_KV2) + 768, us(O_YBF), 768, 1536);
    // 9) ca_o + bias + residual(x1) -> fp32
    k_gemm_bt<64, false, true,  false><<<dim3(64, 6), 256, 0, stream>>>(
        us(O_YBF), us(O_WCO), cao_b, fl(O_X1F), fl(O_RESF), MTOK, 768, 768);
    // 10) LN2 -> x2
    k_ln<true, true><<<MTOK, 256, 0, stream>>>(fl(O_RESF), ln2_g, ln2_b, fl(O_X2F), us(O_X2BF));
    // 11) fc + bias + relu -> bf16
    k_gemm_bt<128, true,  false, true ><<<dim3(32, 24), 256, 0, stream>>>(
        us(O_X2BF), us(O_WFC), fc_b, nullptr, us(O_HBF), MTOK, 3072, 768);
    // 12) fc2 + bias + residual(x2) -> fp32
    k_gemm_bt<64, false, true,  false><<<dim3(64, 6), 256, 0, stream>>>(
        us(O_HBF), us(O_WFC2), fc2_b, fl(O_X2F), fl(O_RESF), MTOK, 768, 3072);
    // 13) LN3 -> out (fp32 only)
    k_ln<true, false><<<MTOK, 256, 0, stream>>>(fl(O_RESF), ln3_g, ln3_b, out, nullptr);
}